// Round 3
// baseline (272.247 us; speedup 1.0000x reference)
//
#include <hip/hip_runtime.h>
#include <math.h>
#include <cstddef>

#define BB 4
#define LL 4096
#define DD 256
#define NST 8
#define RANK 16
#define HID 128
#define BL (BB*LL)          // 16384
#define BLD ((size_t)BL*DD) // 4194304
#define CH 256              // scan chunks
#define CLEN 16             // steps per chunk (CH*CLEN == LL)
#define XZS 512             // xz row stride (xin cols 0..255, z cols 256..511)

typedef __bf16 bf16x8 __attribute__((ext_vector_type(8)));
typedef float  f32x4  __attribute__((ext_vector_type(4)));

__device__ __forceinline__ float siluf(float x){ return x / (1.f + __expf(-x)); }
__device__ __forceinline__ float softplus_fast(float x){
  float r = __logf(1.f + __expf(x));
  return x > 15.f ? x : r;
}
// fp32 -> bf16 bits, round-to-nearest-even
__device__ __forceinline__ unsigned short f2bf(float x){
  union { float f; unsigned u; } v; v.f = x;
  unsigned r = v.u + 0x7fffu + ((v.u >> 16) & 1u);
  return (unsigned short)(r >> 16);
}
__device__ __forceinline__ float bf2f(unsigned short u){
  union { unsigned u32; float f; } c; c.u32 = ((unsigned)u) << 16;
  return c.f;
}

// ---------------- RMSNorm: both streams -> bf16 ----------------------------------
__global__ __launch_bounds__(64) void rms_kernel(
    const float* __restrict__ x0, const float* __restrict__ w0, unsigned short* __restrict__ o0b,
    const float* __restrict__ x1, const float* __restrict__ w1, unsigned short* __restrict__ o1b)
{
  const float* x; const float* w; unsigned short* o;
  if (blockIdx.y == 0){ x = x0; w = w0; o = o0b; } else { x = x1; w = w1; o = o1b; }
  size_t tok = blockIdx.x;
  int lane = threadIdx.x;
  float4 v = ((const float4*)(x + tok*DD))[lane];
  float s = v.x*v.x + v.y*v.y + v.z*v.z + v.w*v.w;
  #pragma unroll
  for (int m = 1; m < 64; m <<= 1) s += __shfl_xor(s, m, 64);
  float scale = 1.f / (sqrtf(s) * (1.f/16.f) + 1e-6f);
  float4 wv = ((const float4*)w)[lane];
  ushort4 r;
  r.x = f2bf(v.x*scale*wv.x); r.y = f2bf(v.y*scale*wv.y);
  r.z = f2bf(v.z*scale*wv.z); r.w = f2bf(v.w*scale*wv.w);
  ((ushort4*)(o + tok*DD))[lane] = r;
}

// ---------------- weight fp32->bf16 conversion -----------------------------------
__global__ __launch_bounds__(256) void cvt1_kernel(
    const float* __restrict__ s, unsigned short* __restrict__ d, int n)
{
  int i = blockIdx.x*256 + threadIdx.x;
  if (i < n) d[i] = f2bf(s[i]);
}
// xproj_f(8192) | xproj_bw(8192) | out_proj(65536) | fc1(32768) | fc2(32768)
__global__ __launch_bounds__(256) void cvt5_kernel(
    const float* __restrict__ s0, const float* __restrict__ s1,
    const float* __restrict__ s2, const float* __restrict__ s3,
    const float* __restrict__ s4, unsigned short* __restrict__ d)
{
  int i = blockIdx.x*256 + threadIdx.x;   // 0..147455
  if (i >= 147456) return;
  float v;
  if (i < 8192)        v = s0[i];
  else if (i < 16384)  v = s1[i - 8192];
  else if (i < 81920)  v = s2[i - 16384];
  else if (i < 114688) v = s3[i - 81920];
  else                 v = s4[i - 114688];
  d[i] = f2bf(v);
}

// ---------------- bf16 MFMA GEMM, 64x64 tile, BK=64: C = A @ Bw^T (+ epilogue) ---
// EPI: 0 = C=acc ; 1 = C=acc+Add & Cb=bf16(C) ; 2 = C=acc+Add ; 3 = Cb=bf16(acc)
// ldc = row stride of C/Cb/Add (for writing into a wider matrix)
template<int EPI>
__global__ __launch_bounds__(256) void gemm_mfma(
    const unsigned short* __restrict__ A, const unsigned short* __restrict__ Bw,
    float* __restrict__ C, const float* __restrict__ Add,
    unsigned short* __restrict__ Cb, int M, int ldc, int K)
{
  constexpr int BK = 64, PAD = 8;
  __shared__ __align__(16) unsigned short As[64][BK+PAD];
  __shared__ __align__(16) unsigned short Bs[64][BK+PAD];
  int tid  = threadIdx.x;
  int row0 = blockIdx.x * 64;
  int col0 = blockIdx.y * 64;
  int wave = tid >> 6, lane = tid & 63;
  int wm = (wave >> 1) * 32, wn = (wave & 1) * 32;
  int lm = lane & 15, kq = lane >> 4;
  int sr = tid >> 2, sc16 = (tid & 3) * 16;

  f32x4 acc[2][2];
  #pragma unroll
  for (int i = 0; i < 2; i++)
    #pragma unroll
    for (int j = 0; j < 2; j++) acc[i][j] = (f32x4){0.f,0.f,0.f,0.f};

  for (int k0 = 0; k0 < K; k0 += BK){
    const unsigned short* ap = &A [(size_t)(row0 + sr)*K + k0 + sc16];
    const unsigned short* bp = &Bw[(size_t)(col0 + sr)*K + k0 + sc16];
    *(int4*)&As[sr][sc16]   = *(const int4*)ap;
    *(int4*)&As[sr][sc16+8] = *(const int4*)(ap + 8);
    *(int4*)&Bs[sr][sc16]   = *(const int4*)bp;
    *(int4*)&Bs[sr][sc16+8] = *(const int4*)(bp + 8);
    __syncthreads();
    #pragma unroll
    for (int ks = 0; ks < 2; ks++){
      bf16x8 af[2], bfv[2];
      #pragma unroll
      for (int i = 0; i < 2; i++) af[i]  = *(const bf16x8*)&As[wm + i*16 + lm][ks*32 + kq*8];
      #pragma unroll
      for (int j = 0; j < 2; j++) bfv[j] = *(const bf16x8*)&Bs[wn + j*16 + lm][ks*32 + kq*8];
      #pragma unroll
      for (int i = 0; i < 2; i++)
        #pragma unroll
        for (int j = 0; j < 2; j++)
          acc[i][j] = __builtin_amdgcn_mfma_f32_16x16x32_bf16(af[i], bfv[j], acc[i][j], 0, 0, 0);
    }
    __syncthreads();
  }

  // C/D layout: col = lane&15, row = (lane>>4)*4 + reg   [m89-verified]
  #pragma unroll
  for (int i = 0; i < 2; i++){
    int rbase = row0 + wm + i*16 + kq*4;
    #pragma unroll
    for (int j = 0; j < 2; j++){
      int col = col0 + wn + j*16 + lm;
      #pragma unroll
      for (int r = 0; r < 4; r++){
        size_t idx = (size_t)(rbase + r)*ldc + col;
        float v = acc[i][j][r];
        if constexpr (EPI == 1 || EPI == 2) v += Add[idx];
        if constexpr (EPI != 3) C[idx] = v;
        if constexpr (EPI == 1 || EPI == 3) Cb[idx] = f2bf(v);
      }
    }
  }
}

// =================== Front: conv+silu+delta + local scan w/ C-apply ==============
// SPLIT-PHASE (round-1 structure; the merged loop regressed 43.6->67 us because
// the compiler wouldn't pipeline step i+1's transcendental front-end under step
// i's serial scan). Phase 1: all 16 steps' conv/dt/softplus with full ILP into
// packX. Phase 2: serial scan; dA powers via depth-3 tree (e2/e4) so the 8
// h-updates are independent (old dA*=e1 chain was depth 7 on the critical path).
__global__ __launch_bounds__(256) void front_kernel(
    const unsigned short* __restrict__ xz,
    const float* __restrict__ xd,
    const float* __restrict__ cwf, const float* __restrict__ cbf,
    const float* __restrict__ cwb, const float* __restrict__ cbb,
    const float* __restrict__ dtwf, const float* __restrict__ dtbf,
    const float* __restrict__ dtwb, const float* __restrict__ dtbb,
    const float* __restrict__ Alogf, const float* __restrict__ Alogb,
    const float* __restrict__ Dfp, const float* __restrict__ Dbp,
    unsigned int* __restrict__ xde,
    float* __restrict__ Sp, float* __restrict__ Hout)
{
  int chunk = blockIdx.x, b = blockIdx.y, dir = blockIdx.z;
  int s0 = chunk*CLEN;
  int d  = threadIdx.x;

  __shared__ float sdt[CLEN][16];   // 1 KB
  __shared__ float sB [CLEN][8];    // 0.5 KB
  __shared__ float sC [CLEN][8];    // 0.5 KB
  #pragma unroll
  for (int e = threadIdx.x; e < CLEN*32; e += 256){
    int lt = e >> 5, col = e & 31;
    int pos = s0 + lt;
    int row = dir ? (LL-1-pos) : pos;
    float v = xd[((size_t)b*LL + row)*64 + dir*32 + col];
    if (col < 16)      sdt[lt][col]    = v;
    else if (col < 24) sB [lt][col-16] = v;
    else               sC [lt][col-24] = v;
  }
  __syncthreads();

  float4 cw = ((const float4*)(dir ? cwb : cwf))[d];
  float cb  = (dir ? cbb : cbf)[d];
  const float* dtw = (dir ? dtwb : dtwf) + d*RANK;
  float4 w0 = ((const float4*)dtw)[0], w1 = ((const float4*)dtw)[1];
  float4 w2 = ((const float4*)dtw)[2], w3 = ((const float4*)dtw)[3];
  float dtb = (dir ? dtbb : dtbf)[d];
  float Dd  = (dir ? Dbp : Dfp)[d];

  const unsigned short* xp = xz + (size_t)b*LL*XZS + d;
  #define LDX(pos) ((pos) >= 0 ? bf2f(xp[(size_t)(dir ? (LL-1-(pos)) : (pos))*XZS]) : 0.f)

  // ---- phase 1: conv + silu + delta, packed into regs (full ILP) ----
  float xv[CLEN+3];
  xv[0] = LDX(s0-3); xv[1] = LDX(s0-2); xv[2] = LDX(s0-1);
  #pragma unroll
  for (int i = 0; i < CLEN; i++) xv[3+i] = LDX(s0+i);
  #undef LDX

  unsigned packX[CLEN];
  #pragma unroll
  for (int i = 0; i < CLEN; i++){
    float xc = cb;
    xc = fmaf(cw.x, xv[i],   xc); xc = fmaf(cw.y, xv[i+1], xc);
    xc = fmaf(cw.z, xv[i+2], xc); xc = fmaf(cw.w, xv[i+3], xc);
    xc = siluf(xc);
    const float* dt = &sdt[i][0];
    float de = dtb;
    de = fmaf(dt[0],w0.x, fmaf(dt[1],w0.y, fmaf(dt[2],w0.z, fmaf(dt[3],w0.w, de))));
    de = fmaf(dt[4],w1.x, fmaf(dt[5],w1.y, fmaf(dt[6],w1.z, fmaf(dt[7],w1.w, de))));
    de = fmaf(dt[8],w2.x, fmaf(dt[9],w2.y, fmaf(dt[10],w2.z, fmaf(dt[11],w2.w, de))));
    de = fmaf(dt[12],w3.x, fmaf(dt[13],w3.y, fmaf(dt[14],w3.z, fmaf(dt[15],w3.w, de))));
    de = softplus_fast(de);
    packX[i] = (unsigned)f2bf(xc) | ((unsigned)f2bf(de) << 16);
  }

  // ---- phase 2: local scan (h from 0) with C-apply; write pack (y0,de) ----
  const float* Alog = dir ? Alogb : Alogf;
  float A[NST];
  bool fast = true;
  #pragma unroll
  for (int n = 0; n < NST; n++){
    A[n] = -__expf(Alog[d*NST + n]);
    fast = fast && (fabsf(A[n] + (float)(n+1)) < 1e-3f);
  }
  float h[NST];
  #pragma unroll
  for (int n = 0; n < NST; n++) h[n] = 0.f;
  float S = 0.f;

  unsigned int* xout = xde + ((size_t)(dir*BB + b)*LL + s0)*DD + d;

  if (fast){
    #pragma unroll
    for (int t = 0; t < CLEN; t++){
      unsigned pk = packX[t];
      float xc = bf2f((unsigned short)(pk & 0xffffu));
      float de = bf2f((unsigned short)(pk >> 16));
      S += de;
      float dux = de * xc;
      const float* Bv = &sB[t][0];
      const float* Cv = &sC[t][0];
      float e1 = __expf(-de);
      float e2 = e1*e1, e3 = e2*e1, e4 = e2*e2;
      float e5 = e4*e1, e6 = e4*e2, e7 = e4*e3, e8 = e4*e4;
      float acc = xc * Dd;
      h[0] = fmaf(e1, h[0], dux*Bv[0]); acc = fmaf(h[0], Cv[0], acc);
      h[1] = fmaf(e2, h[1], dux*Bv[1]); acc = fmaf(h[1], Cv[1], acc);
      h[2] = fmaf(e3, h[2], dux*Bv[2]); acc = fmaf(h[2], Cv[2], acc);
      h[3] = fmaf(e4, h[3], dux*Bv[3]); acc = fmaf(h[3], Cv[3], acc);
      h[4] = fmaf(e5, h[4], dux*Bv[4]); acc = fmaf(h[4], Cv[4], acc);
      h[5] = fmaf(e6, h[5], dux*Bv[5]); acc = fmaf(h[5], Cv[5], acc);
      h[6] = fmaf(e7, h[6], dux*Bv[6]); acc = fmaf(h[6], Cv[6], acc);
      h[7] = fmaf(e8, h[7], dux*Bv[7]); acc = fmaf(h[7], Cv[7], acc);
      xout[(size_t)t*DD] = (pk & 0xffff0000u) | (unsigned)f2bf(acc);
    }
  } else {
    #pragma unroll
    for (int t = 0; t < CLEN; t++){
      unsigned pk = packX[t];
      float xc = bf2f((unsigned short)(pk & 0xffffu));
      float de = bf2f((unsigned short)(pk >> 16));
      S += de;
      float dux = de * xc;
      const float* Bv = &sB[t][0];
      const float* Cv = &sC[t][0];
      float acc = xc * Dd;
      #pragma unroll
      for (int n = 0; n < NST; n++){
        h[n] = fmaf(__expf(de*A[n]), h[n], dux*Bv[n]);
        acc = fmaf(h[n], Cv[n], acc);
      }
      xout[(size_t)t*DD] = (pk & 0xffff0000u) | (unsigned)f2bf(acc);
    }
  }

  size_t ob = ((((size_t)dir*CH + chunk)*BB + b)*DD + d)*NST;
  float4 h0v, h1v;
  h0v.x=h[0]; h0v.y=h[1]; h0v.z=h[2]; h0v.w=h[3];
  h1v.x=h[4]; h1v.y=h[5]; h1v.z=h[6]; h1v.w=h[7];
  *(float4*)&Hout[ob]   = h0v; *(float4*)&Hout[ob+4] = h1v;
  Sp[((size_t)(dir*CH + chunk)*BB + b)*DD + d] = S;
}

// Phase 2: chunk-carry scan, 2-level. Block = (dir,b,d) -> 2048 one-wave blocks.
// Lane = (seg, n): 8 segments x 32 chunks, 8 states. Chunk decay p_c =
// exp(S_c*A[n]); segment decay = exp(sum(S)*A[n]). Pair-scan across segments via
// shfl_up, then seeded re-apply from registers. H rewritten in place.
__global__ __launch_bounds__(64) void scan_p2(
    const float* __restrict__ Sp, float* H,
    const float* __restrict__ Alogf, const float* __restrict__ Alogb)
{
  const int SEGC = CH/8;    // 32 chunks per segment
  int blk = blockIdx.x;
  int d   = blk & (DD-1);
  int b   = (blk >> 8) & (BB-1);
  int dir = blk >> 10;
  int t   = threadIdx.x;
  int seg = t >> 3, n = t & 7;
  float A = -__expf((dir ? Alogb : Alogf)[d*NST + n]);

  const size_t sstr = (size_t)BB*DD;          // per-chunk stride in Sp
  const size_t hstr = (size_t)BB*DD*NST;      // per-chunk stride in H
  size_t sb = (size_t)dir*CH*sstr + (size_t)b*DD + d;
  size_t hb = (size_t)dir*CH*hstr + ((size_t)b*DD + d)*NST + n;
  int c0 = seg*SEGC;

  float pv[SEGC], hv[SEGC];
  #pragma unroll
  for (int k = 0; k < SEGC; k++){
    pv[k] = Sp[sb + (size_t)(c0+k)*sstr];
    hv[k] = H [hb + (size_t)(c0+k)*hstr];
  }
  float h = 0.f, Ss = 0.f;
  #pragma unroll
  for (int k = 0; k < SEGC; k++){
    Ss += pv[k];
    pv[k] = __expf(pv[k]*A);
    h = fmaf(pv[k], h, hv[k]);
  }
  float pi = __expf(Ss*A), hi = h;
  #pragma unroll
  for (int off = 8; off < 64; off <<= 1){
    float hprev = __shfl_up(hi, off, 64);
    float pprev = __shfl_up(pi, off, 64);
    if (t >= off){ hi = fmaf(pi, hprev, hi); pi *= pprev; }
  }
  float hin = __shfl_up(hi, 8, 64);
  h = (seg == 0) ? 0.f : hin;
  #pragma unroll
  for (int k = 0; k < SEGC; k++){
    size_t idx = hb + (size_t)(c0+k)*hstr;
    H[idx] = h;
    h = fmaf(pv[k], h, hv[k]);
  }
}

// =================== Back: correction + combine + rmsnorm + gate ==================
// Block (c,b) handles fwd chunk c and bwd chunk CH-1-c: both cover the SAME token
// range [16c, 16c+16). Computes both corrections in fp32, averages, per-token RMS
// reduce in-block, gates with silu(z), writes ycomb bf16.
__global__ __launch_bounds__(256) void back_kernel(
    const unsigned int* __restrict__ xde,
    const float* __restrict__ xd,
    const float* __restrict__ Alogf, const float* __restrict__ Alogb,
    const float* __restrict__ Hin,
    const unsigned short* __restrict__ xz,
    const float* __restrict__ wn,
    unsigned short* __restrict__ outb)
{
  int c  = blockIdx.x, b = blockIdx.y;
  int cbk = CH-1-c;
  int d  = threadIdx.x;
  int T0 = c*CLEN;          // token base (fwd storage base)
  int Pb = cbk*CLEN;        // bwd storage base; storage Pb+k <-> token T0+15-k

  __shared__ float sCf[CLEN][8], sCb[CLEN][8];  // 1 KB
  __shared__ float red[CLEN][4];
  __shared__ float sscale[CLEN];
  {
    int k  = threadIdx.x & 7;
    int lt = (threadIdx.x >> 3) & 15;
    if (threadIdx.x < 128)
      sCf[lt][k] = xd[((size_t)b*LL + T0 + lt)*64 + 24 + k];
    else
      sCb[lt][k] = xd[((size_t)b*LL + (T0 + 15 - lt))*64 + 56 + k];
  }
  __syncthreads();

  float Af[NST], Ab[NST];
  bool fast = true;
  #pragma unroll
  for (int n = 0; n < NST; n++){
    Af[n] = -__expf(Alogf[d*NST + n]);
    Ab[n] = -__expf(Alogb[d*NST + n]);
    fast = fast && (fabsf(Af[n] + (float)(n+1)) < 1e-3f)
                && (fabsf(Ab[n] + (float)(n+1)) < 1e-3f);
  }

  float vf[CLEN];

  // ---- forward correction ----
  {
    float hn[NST];
    size_t ib = (((size_t)c*BB + b)*DD + d)*NST;                 // dir=0
    float4 a0 = *(const float4*)&Hin[ib];
    float4 a1 = *(const float4*)&Hin[ib+4];
    hn[0]=a0.x; hn[1]=a0.y; hn[2]=a0.z; hn[3]=a0.w;
    hn[4]=a1.x; hn[5]=a1.y; hn[6]=a1.z; hn[7]=a1.w;
    const unsigned int* p = xde + ((size_t)b*LL + T0)*DD + d;    // dir=0 plane
    unsigned int pk[CLEN];
    #pragma unroll
    for (int t = 0; t < CLEN; t++) pk[t] = p[(size_t)t*DD];
    float S = 0.f;
    if (fast){
      #pragma unroll
      for (int t = 0; t < CLEN; t++){
        float y0 = bf2f((unsigned short)(pk[t] & 0xffffu));
        float de = bf2f((unsigned short)(pk[t] >> 16));
        S += de;
        float E1 = __expf(-S);
        float E2 = E1*E1, E3 = E2*E1, E4 = E2*E2;
        float E5 = E4*E1, E6 = E4*E2, E7 = E4*E3, E8 = E4*E4;
        float corr =      E1 * (hn[0]*sCf[t][0]);
        corr = fmaf(E2, hn[1]*sCf[t][1], corr);
        corr = fmaf(E3, hn[2]*sCf[t][2], corr);
        corr = fmaf(E4, hn[3]*sCf[t][3], corr);
        corr = fmaf(E5, hn[4]*sCf[t][4], corr);
        corr = fmaf(E6, hn[5]*sCf[t][5], corr);
        corr = fmaf(E7, hn[6]*sCf[t][6], corr);
        corr = fmaf(E8, hn[7]*sCf[t][7], corr);
        vf[t] = y0 + corr;
      }
    } else {
      #pragma unroll
      for (int t = 0; t < CLEN; t++){
        float y0 = bf2f((unsigned short)(pk[t] & 0xffffu));
        float de = bf2f((unsigned short)(pk[t] >> 16));
        S += de;
        float corr = 0.f;
        #pragma unroll
        for (int n = 0; n < NST; n++)
          corr = fmaf(__expf(S*Af[n]), hn[n]*sCf[t][n], corr);
        vf[t] = y0 + corr;
      }
    }
  }

  // ---- backward correction, merged into vf (token j pairs with bwd k=15-j) ----
  {
    float hn[NST];
    size_t ib = ((((size_t)CH + cbk)*BB + b)*DD + d)*NST;        // dir=1
    float4 a0 = *(const float4*)&Hin[ib];
    float4 a1 = *(const float4*)&Hin[ib+4];
    hn[0]=a0.x; hn[1]=a0.y; hn[2]=a0.z; hn[3]=a0.w;
    hn[4]=a1.x; hn[5]=a1.y; hn[6]=a1.z; hn[7]=a1.w;
    const unsigned int* p = xde + ((size_t)(BB + b)*LL + Pb)*DD + d;  // dir=1 plane
    unsigned int pk[CLEN];
    #pragma unroll
    for (int t = 0; t < CLEN; t++) pk[t] = p[(size_t)t*DD];
    float S = 0.f;
    if (fast){
      #pragma unroll
      for (int t = 0; t < CLEN; t++){
        float y0 = bf2f((unsigned short)(pk[t] & 0xffffu));
        float de = bf2f((unsigned short)(pk[t] >> 16));
        S += de;
        float E1 = __expf(-S);
        float E2 = E1*E1, E3 = E2*E1, E4 = E2*E2;
        float E5 = E4*E1, E6 = E4*E2, E7 = E4*E3, E8 = E4*E4;
        float corr =      E1 * (hn[0]*sCb[t][0]);
        corr = fmaf(E2, hn[1]*sCb[t][1], corr);
        corr = fmaf(E3, hn[2]*sCb[t][2], corr);
        corr = fmaf(E4, hn[3]*sCb[t][3], corr);
        corr = fmaf(E5, hn[4]*sCb[t][4], corr);
        corr = fmaf(E6, hn[5]*sCb[t][5], corr);
        corr = fmaf(E7, hn[6]*sCb[t][6], corr);
        corr = fmaf(E8, hn[7]*sCb[t][7], corr);
        int j = 15 - t;
        vf[j] = 0.5f*(vf[j] + y0 + corr);
      }
    } else {
      #pragma unroll
      for (int t = 0; t < CLEN; t++){
        float y0 = bf2f((unsigned short)(pk[t] & 0xffffu));
        float de = bf2f((unsigned short)(pk[t] >> 16));
        S += de;
        float corr = 0.f;
        #pragma unroll
        for (int n = 0; n < NST; n++)
          corr = fmaf(__expf(S*Ab[n]), hn[n]*sCb[t][n], corr);
        int j = 15 - t;
        vf[j] = 0.5f*(vf[j] + y0 + corr);
      }
    }
  }

  // ---- per-token RMS reduce over d ----
  int wave = d >> 6, lane = d & 63;
  #pragma unroll
  for (int j = 0; j < CLEN; j++){
    float s = vf[j]*vf[j];
    #pragma unroll
    for (int m = 1; m < 64; m <<= 1) s += __shfl_xor(s, m, 64);
    if (lane == 0) red[j][wave] = s;
  }
  __syncthreads();
  if (d < CLEN){
    float s = red[d][0] + red[d][1] + red[d][2] + red[d][3];
    sscale[d] = 1.f / (sqrtf(s)*(1.f/16.f) + 1e-6f);
  }
  __syncthreads();

  float wd = wn[d];
  #pragma unroll
  for (int j = 0; j < CLEN; j++){
    size_t tok = (size_t)b*LL + T0 + j;
    float z = bf2f(xz[tok*XZS + 256 + d]);
    outb[tok*DD + d] = f2bf(vf[j]*sscale[j]*wd*siluf(z));
  }
}

// ---------------- FF depthwise conv k=3 pad(1,1) + SiLU -> bf16 ------------------
__global__ __launch_bounds__(256) void dwconv3_kernel(
    const float* __restrict__ m, const float* __restrict__ w,
    const float* __restrict__ bi, unsigned short* __restrict__ o)
{
  size_t gid = (size_t)blockIdx.x*256 + threadIdx.x;  // over BL*HID
  int c = (int)(gid % HID);
  int tok = (int)(gid / HID);
  int b = tok / LL, t = tok % LL;
  float acc = bi[c];
  #pragma unroll
  for (int k = 0; k < 3; k++){
    int tt = t - 1 + k;
    if (tt >= 0 && tt < LL)
      acc = fmaf(w[c*3 + k], m[((size_t)b*LL + tt)*HID + c], acc);
  }
  o[gid] = f2bf(siluf(acc));
}

extern "C" void kernel_launch(void* const* d_in, const int* in_sizes, int n_in,
                              void* d_out, int out_size, void* d_ws, size_t ws_size,
                              hipStream_t stream)
{
  const float* x0        = (const float*)d_in[0];
  const float* x1        = (const float*)d_in[1];
  const float* w_norm0   = (const float*)d_in[2];
  const float* w_norm1   = (const float*)d_in[3];
  const float* in_proj_w = (const float*)d_in[4];
  const float* conv_w_f  = (const float*)d_in[5];
  const float* conv_b_f  = (const float*)d_in[6];
  const float* xproj_w_f = (const float*)d_in[7];
  const float* dtproj_w_f= (const float*)d_in[8];
  const float* dtproj_b_f= (const float*)d_in[9];
  const float* A_log_f   = (const float*)d_in[10];
  const float* D_f       = (const float*)d_in[11];
  const float* conv_w_bw = (const float*)d_in[12];
  const float* conv_b_bw = (const float*)d_in[13];
  const float* xproj_w_bw= (const float*)d_in[14];
  const float* dtproj_w_bw=(const float*)d_in[15];
  const float* dtproj_b_bw=(const float*)d_in[16];
  const float* A_log_bw  = (const float*)d_in[17];
  const float* D_bw      = (const float*)d_in[18];
  const float* norm_y_w  = (const float*)d_in[19];
  const float* out_proj_w= (const float*)d_in[20];
  const float* fc1_w     = (const float*)d_in[21];
  const float* dw_w      = (const float*)d_in[22];
  const float* dw_b      = (const float*)d_in[23];
  const float* fc2_w     = (const float*)d_in[24];
  float* out = (float*)d_out;
  float* ws  = (float*)d_ws;

  // region map (floats, BLD each), lifetime-reused
  float* r0 = ws + 0*BLD;   // h0b (bf16) -> ycomb_b (bf16)
  float* r1 = ws + 1*BLD;   // h1b (bf16)
  float* r2 = ws + 2*BLD;   // xz_b (bf16, BL x 512 = full region)
  float* r3 = ws + 3*BLD;   // xd (fp32 BLx64, 4MB) -- live through back_kernel
  float* r4 = ws + 4*BLD;   // xde pack (y0,de) (uint32, spans r4+r5) -> m1 (fp32)
  float* r5 = ws + 5*BLD;   //                                       -> m2b (bf16)
  float* r6 = ws + 6*BLD;   // wbuf1 (bf16 in_proj) -> Hout (= Hin, in-place p2)
  float* r7 = ws + 7*BLD;   // wbuf2 (bf16 weights) + xb (bf16) + S-plane (tail)

  unsigned short* h0b   = (unsigned short*)r0;
  unsigned short* h1b   = (unsigned short*)r1;
  unsigned short* xz_b  = (unsigned short*)r2;   // BL x XZS
  float*          xd    = r3;                    // BL x 64 fp32
  unsigned int*   xde   = (unsigned int*)r4;     // 2*BLD dwords = r4+r5
  unsigned short* wbuf1 = (unsigned short*)r6;   // 131072 (512x256)
  float* Hout = r6;                              // 2*CH*BB*DD*NST = BLD floats
  float* Hin  = Hout;                            // p2 rewrites in place
  const size_t SPLANE = (size_t)2*CH*BB*DD;      // 524288 floats (2 MB)
  float* Sp   = r7 + (BLD - SPLANE);             // tail of r7 (disjoint from wbuf2/xb)
  unsigned short* ycomb_b = (unsigned short*)r0; // r0 free after gemm xz (h0b dead)
  unsigned short* wbuf2   = (unsigned short*)r7;
  unsigned short* wb_xp   = wbuf2;               // 16384  (64x256)
  unsigned short* wb_out  = wbuf2 + 16384;       // 65536
  unsigned short* wb_fc1  = wbuf2 + 81920;       // 32768
  unsigned short* wb_fc2  = wbuf2 + 114688;      // 32768
  unsigned short* xb      = wbuf2 + 147456;      // BLD bf16
  float*          m1      = r4;
  unsigned short* m2b     = (unsigned short*)r5;

  // 0. weight conversions
  cvt1_kernel<<<dim3(512), 256, 0, stream>>>(in_proj_w, wbuf1, 131072);
  cvt5_kernel<<<dim3(576), 256, 0, stream>>>(
      xproj_w_f, xproj_w_bw, out_proj_w, fc1_w, fc2_w, wbuf2);

  // 1. RMSNorm x0 -> h0b, x1 -> h1b (both bf16)
  rms_kernel<<<dim3(BL,2), 64, 0, stream>>>(x0, w_norm0, h0b, x1, w_norm1, h1b);

  // 2. xz = h0 @ in_proj.T -> xz_b (bf16, one N=512 dispatch)
  gemm_mfma<3><<<dim3(BL/64, 8), 256, 0, stream>>>(
      h0b, wbuf1, nullptr, nullptr, xz_b, BL, XZS, 256);

  // 3. merged xproj: xd[t][0..31]=fwd dt/B/C, [32..63]=bwd (natural t order)
  gemm_mfma<0><<<dim3(BL/64, 1), 256, 0, stream>>>(
      h1b, wb_xp, xd, nullptr, nullptr, BL, 64, 256);

  // 4. front: conv+silu+delta + local scan w/ C-apply -> pack(y0,de), S, Hout
  front_kernel<<<dim3(CH, BB, 2), 256, 0, stream>>>(
      xz_b, xd, conv_w_f, conv_b_f, conv_w_bw, conv_b_bw,
      dtproj_w_f, dtproj_b_f, dtproj_w_bw, dtproj_b_bw,
      A_log_f, A_log_bw, D_f, D_bw, xde, Sp, Hout);

  // 5. chunk-carry scan (2-level, in-place Hout->Hin)
  scan_p2<<<dim3(2*BB*DD), 64, 0, stream>>>(Sp, Hout, A_log_f, A_log_bw);

  // 6. fused correction + combine + rmsnorm + gate -> ycomb_b (r0)
  back_kernel<<<dim3(CH, BB), 256, 0, stream>>>(
      xde, xd, A_log_f, A_log_bw, Hin, xz_b, norm_y_w, ycomb_b);

  // 7. x = y @ out_proj.T + residual(x0) -> d_out (fp32) + xb (bf16)
  gemm_mfma<1><<<dim3(BL/64, 4), 256, 0, stream>>>(
      ycomb_b, wb_out, out, x0, xb, BL, 256, 256);

  // 8. m1 = x @ fc1.T (fp32; overwrites dead xde)
  gemm_mfma<0><<<dim3(BL/64, 2), 256, 0, stream>>>(
      xb, wb_fc1, m1, nullptr, nullptr, BL, 128, 256);

  // 9. m2 = silu(dwconv3(m1)) -> bf16
  dwconv3_kernel<<<dim3((BL*HID)/256), 256, 0, stream>>>(m1, dw_w, dw_b, m2b);

  // 10. out = x + m2 @ fc2.T
  gemm_mfma<2><<<dim3(BL/64, 4), 256, 0, stream>>>(
      m2b, wb_fc2, out, out, nullptr, BL, 256, 128);
}

// Round 4
// 266.805 us; speedup vs baseline: 1.0204x; 1.0204x over previous
//
#include <hip/hip_runtime.h>
#include <math.h>
#include <cstddef>

#define BB 4
#define LL 4096
#define DD 256
#define NST 8
#define RANK 16
#define HID 128
#define BL (BB*LL)          // 16384
#define BLD ((size_t)BL*DD) // 4194304
#define CH 256              // scan chunks
#define CLEN 16             // steps per chunk (CH*CLEN == LL)
#define XZS 512             // xz row stride (xin cols 0..255, z cols 256..511)

typedef __bf16 bf16x8 __attribute__((ext_vector_type(8)));
typedef float  f32x4  __attribute__((ext_vector_type(4)));

__device__ __forceinline__ float siluf(float x){ return x / (1.f + __expf(-x)); }
__device__ __forceinline__ float softplus_fast(float x){
  float r = __logf(1.f + __expf(x));
  return x > 15.f ? x : r;
}
// fp32 -> bf16 bits, round-to-nearest-even
__device__ __forceinline__ unsigned short f2bf(float x){
  union { float f; unsigned u; } v; v.f = x;
  unsigned r = v.u + 0x7fffu + ((v.u >> 16) & 1u);
  return (unsigned short)(r >> 16);
}
__device__ __forceinline__ float bf2f(unsigned short u){
  union { unsigned u32; float f; } c; c.u32 = ((unsigned)u) << 16;
  return c.f;
}

// ---------------- RMSNorm: both streams -> bf16 ----------------------------------
__global__ __launch_bounds__(64) void rms_kernel(
    const float* __restrict__ x0, const float* __restrict__ w0, unsigned short* __restrict__ o0b,
    const float* __restrict__ x1, const float* __restrict__ w1, unsigned short* __restrict__ o1b)
{
  const float* x; const float* w; unsigned short* o;
  if (blockIdx.y == 0){ x = x0; w = w0; o = o0b; } else { x = x1; w = w1; o = o1b; }
  size_t tok = blockIdx.x;
  int lane = threadIdx.x;
  float4 v = ((const float4*)(x + tok*DD))[lane];
  float s = v.x*v.x + v.y*v.y + v.z*v.z + v.w*v.w;
  #pragma unroll
  for (int m = 1; m < 64; m <<= 1) s += __shfl_xor(s, m, 64);
  float scale = 1.f / (sqrtf(s) * (1.f/16.f) + 1e-6f);
  float4 wv = ((const float4*)w)[lane];
  ushort4 r;
  r.x = f2bf(v.x*scale*wv.x); r.y = f2bf(v.y*scale*wv.y);
  r.z = f2bf(v.z*scale*wv.z); r.w = f2bf(v.w*scale*wv.w);
  ((ushort4*)(o + tok*DD))[lane] = r;
}

// ---------------- weight fp32->bf16 conversion -----------------------------------
__global__ __launch_bounds__(256) void cvt1_kernel(
    const float* __restrict__ s, unsigned short* __restrict__ d, int n)
{
  int i = blockIdx.x*256 + threadIdx.x;
  if (i < n) d[i] = f2bf(s[i]);
}
// xproj_f(8192) | xproj_bw(8192) | out_proj(65536) | fc1(32768) | fc2(32768)
__global__ __launch_bounds__(256) void cvt5_kernel(
    const float* __restrict__ s0, const float* __restrict__ s1,
    const float* __restrict__ s2, const float* __restrict__ s3,
    const float* __restrict__ s4, unsigned short* __restrict__ d)
{
  int i = blockIdx.x*256 + threadIdx.x;   // 0..147455
  if (i >= 147456) return;
  float v;
  if (i < 8192)        v = s0[i];
  else if (i < 16384)  v = s1[i - 8192];
  else if (i < 81920)  v = s2[i - 16384];
  else if (i < 114688) v = s3[i - 81920];
  else                 v = s4[i - 114688];
  d[i] = f2bf(v);
}

// ---------------- bf16 MFMA GEMM, 64x64 tile, BK=64 (for N=64 xproj) -------------
// EPI: 0 = C=acc ; 1 = C=acc+Add & Cb=bf16(C) ; 2 = C=acc+Add ; 3 = Cb=bf16(acc)
template<int EPI>
__global__ __launch_bounds__(256) void gemm_mfma(
    const unsigned short* __restrict__ A, const unsigned short* __restrict__ Bw,
    float* __restrict__ C, const float* __restrict__ Add,
    unsigned short* __restrict__ Cb, int M, int ldc, int K)
{
  constexpr int BK = 64, PAD = 8;
  __shared__ __align__(16) unsigned short As[64][BK+PAD];
  __shared__ __align__(16) unsigned short Bs[64][BK+PAD];
  int tid  = threadIdx.x;
  int row0 = blockIdx.x * 64;
  int col0 = blockIdx.y * 64;
  int wave = tid >> 6, lane = tid & 63;
  int wm = (wave >> 1) * 32, wn = (wave & 1) * 32;
  int lm = lane & 15, kq = lane >> 4;
  int sr = tid >> 2, sc16 = (tid & 3) * 16;

  f32x4 acc[2][2];
  #pragma unroll
  for (int i = 0; i < 2; i++)
    #pragma unroll
    for (int j = 0; j < 2; j++) acc[i][j] = (f32x4){0.f,0.f,0.f,0.f};

  for (int k0 = 0; k0 < K; k0 += BK){
    const unsigned short* ap = &A [(size_t)(row0 + sr)*K + k0 + sc16];
    const unsigned short* bp = &Bw[(size_t)(col0 + sr)*K + k0 + sc16];
    *(int4*)&As[sr][sc16]   = *(const int4*)ap;
    *(int4*)&As[sr][sc16+8] = *(const int4*)(ap + 8);
    *(int4*)&Bs[sr][sc16]   = *(const int4*)bp;
    *(int4*)&Bs[sr][sc16+8] = *(const int4*)(bp + 8);
    __syncthreads();
    #pragma unroll
    for (int ks = 0; ks < 2; ks++){
      bf16x8 af[2], bfv[2];
      #pragma unroll
      for (int i = 0; i < 2; i++) af[i]  = *(const bf16x8*)&As[wm + i*16 + lm][ks*32 + kq*8];
      #pragma unroll
      for (int j = 0; j < 2; j++) bfv[j] = *(const bf16x8*)&Bs[wn + j*16 + lm][ks*32 + kq*8];
      #pragma unroll
      for (int i = 0; i < 2; i++)
        #pragma unroll
        for (int j = 0; j < 2; j++)
          acc[i][j] = __builtin_amdgcn_mfma_f32_16x16x32_bf16(af[i], bfv[j], acc[i][j], 0, 0, 0);
    }
    __syncthreads();
  }

  // C/D layout: col = lane&15, row = (lane>>4)*4 + reg   [m89-verified]
  #pragma unroll
  for (int i = 0; i < 2; i++){
    int rbase = row0 + wm + i*16 + kq*4;
    #pragma unroll
    for (int j = 0; j < 2; j++){
      int col = col0 + wn + j*16 + lm;
      #pragma unroll
      for (int r = 0; r < 4; r++){
        size_t idx = (size_t)(rbase + r)*ldc + col;
        float v = acc[i][j][r];
        if constexpr (EPI == 1 || EPI == 2) v += Add[idx];
        if constexpr (EPI != 3) C[idx] = v;
        if constexpr (EPI == 1 || EPI == 3) Cb[idx] = f2bf(v);
      }
    }
  }
}

// ---------------- bf16 MFMA GEMM, 128x128 tile, BK=64 ----------------------------
// 4 waves in 2x2; each wave computes a 64x64 quadrant = 4x4 16x16 fragments.
// Same fragment/epilogue mapping as gemm_mfma (verified), same PAD=8 layout
// (0 bank conflicts measured). ~4x the MFMA per barrier pair of the 64-tile.
template<int EPI>
__global__ __launch_bounds__(256) void gemm128(
    const unsigned short* __restrict__ A, const unsigned short* __restrict__ Bw,
    float* __restrict__ C, const float* __restrict__ Add,
    unsigned short* __restrict__ Cb, int ldc, int K)
{
  constexpr int BK = 64, PAD = 8;
  __shared__ __align__(16) unsigned short As[128][BK+PAD];
  __shared__ __align__(16) unsigned short Bs[128][BK+PAD];
  int tid  = threadIdx.x;
  int row0 = blockIdx.x * 128;
  int col0 = blockIdx.y * 128;
  int wave = tid >> 6, lane = tid & 63;
  int wm = (wave >> 1) * 64, wn = (wave & 1) * 64;
  int lm = lane & 15, kq = lane >> 4;

  f32x4 acc[4][4];
  #pragma unroll
  for (int i = 0; i < 4; i++)
    #pragma unroll
    for (int j = 0; j < 4; j++) acc[i][j] = (f32x4){0.f,0.f,0.f,0.f};

  for (int k0 = 0; k0 < K; k0 += BK){
    // stage 128x64 bf16 per matrix: 1024 int4, 4 per thread, coalesced
    #pragma unroll
    for (int q = 0; q < 4; q++){
      int l = tid + 256*q;            // 0..1023
      int r = l >> 3, c8 = (l & 7) * 8;
      *(int4*)&As[r][c8] = *(const int4*)&A [(size_t)(row0 + r)*K + k0 + c8];
      *(int4*)&Bs[r][c8] = *(const int4*)&Bw[(size_t)(col0 + r)*K + k0 + c8];
    }
    __syncthreads();
    #pragma unroll
    for (int ks = 0; ks < 2; ks++){
      bf16x8 af[4], bfv[4];
      #pragma unroll
      for (int i = 0; i < 4; i++) af[i]  = *(const bf16x8*)&As[wm + i*16 + lm][ks*32 + kq*8];
      #pragma unroll
      for (int j = 0; j < 4; j++) bfv[j] = *(const bf16x8*)&Bs[wn + j*16 + lm][ks*32 + kq*8];
      #pragma unroll
      for (int i = 0; i < 4; i++)
        #pragma unroll
        for (int j = 0; j < 4; j++)
          acc[i][j] = __builtin_amdgcn_mfma_f32_16x16x32_bf16(af[i], bfv[j], acc[i][j], 0, 0, 0);
    }
    __syncthreads();
  }

  #pragma unroll
  for (int i = 0; i < 4; i++){
    int rbase = row0 + wm + i*16 + kq*4;
    #pragma unroll
    for (int j = 0; j < 4; j++){
      int col = col0 + wn + j*16 + lm;
      #pragma unroll
      for (int r = 0; r < 4; r++){
        size_t idx = (size_t)(rbase + r)*ldc + col;
        float v = acc[i][j][r];
        if constexpr (EPI == 1 || EPI == 2) v += Add[idx];
        if constexpr (EPI != 3) C[idx] = v;
        if constexpr (EPI == 1 || EPI == 3) Cb[idx] = f2bf(v);
      }
    }
  }
}

// =================== Front: conv+silu+delta + local scan w/ C-apply ==============
// ROUND-1 STRUCTURE (measured 43.6us, VGPR 80): split-phase (phase 1 = all 16
// steps' conv/dt/softplus with full ILP into packX; phase 2 = serial scan with
// the dA*=e1 chain). The e1..e8 power tree (r3) raised VGPR 88 / dropped
// occupancy -> 54us; the merged loop (r2) killed pipelining -> 67us. Keep chain.
__global__ __launch_bounds__(256) void front_kernel(
    const unsigned short* __restrict__ xz,
    const float* __restrict__ xd,
    const float* __restrict__ cwf, const float* __restrict__ cbf,
    const float* __restrict__ cwb, const float* __restrict__ cbb,
    const float* __restrict__ dtwf, const float* __restrict__ dtbf,
    const float* __restrict__ dtwb, const float* __restrict__ dtbb,
    const float* __restrict__ Alogf, const float* __restrict__ Alogb,
    const float* __restrict__ Dfp, const float* __restrict__ Dbp,
    unsigned int* __restrict__ xde,
    float* __restrict__ Sp, float* __restrict__ Hout)
{
  int chunk = blockIdx.x, b = blockIdx.y, dir = blockIdx.z;
  int s0 = chunk*CLEN;
  int d  = threadIdx.x;

  __shared__ float sdt[CLEN][16];   // 1 KB
  __shared__ float sB [CLEN][8];    // 0.5 KB
  __shared__ float sC [CLEN][8];    // 0.5 KB
  #pragma unroll
  for (int e = threadIdx.x; e < CLEN*32; e += 256){
    int lt = e >> 5, col = e & 31;
    int pos = s0 + lt;
    int row = dir ? (LL-1-pos) : pos;
    float v = xd[((size_t)b*LL + row)*64 + dir*32 + col];
    if (col < 16)      sdt[lt][col]    = v;
    else if (col < 24) sB [lt][col-16] = v;
    else               sC [lt][col-24] = v;
  }
  __syncthreads();

  float4 cw = ((const float4*)(dir ? cwb : cwf))[d];
  float cb  = (dir ? cbb : cbf)[d];
  const float* dtw = (dir ? dtwb : dtwf) + d*RANK;
  float4 w0 = ((const float4*)dtw)[0], w1 = ((const float4*)dtw)[1];
  float4 w2 = ((const float4*)dtw)[2], w3 = ((const float4*)dtw)[3];
  float dtb = (dir ? dtbb : dtbf)[d];
  float Dd  = (dir ? Dbp : Dfp)[d];

  const unsigned short* xp = xz + (size_t)b*LL*XZS + d;
  #define LDX(pos) ((pos) >= 0 ? bf2f(xp[(size_t)(dir ? (LL-1-(pos)) : (pos))*XZS]) : 0.f)

  // ---- phase 1: conv + silu + delta, packed into regs (full ILP) ----
  float xv[CLEN+3];
  xv[0] = LDX(s0-3); xv[1] = LDX(s0-2); xv[2] = LDX(s0-1);
  #pragma unroll
  for (int i = 0; i < CLEN; i++) xv[3+i] = LDX(s0+i);
  #undef LDX

  unsigned packX[CLEN];
  #pragma unroll
  for (int i = 0; i < CLEN; i++){
    float xc = cb;
    xc = fmaf(cw.x, xv[i],   xc); xc = fmaf(cw.y, xv[i+1], xc);
    xc = fmaf(cw.z, xv[i+2], xc); xc = fmaf(cw.w, xv[i+3], xc);
    xc = siluf(xc);
    const float* dt = &sdt[i][0];
    float de = dtb;
    de = fmaf(dt[0],w0.x, fmaf(dt[1],w0.y, fmaf(dt[2],w0.z, fmaf(dt[3],w0.w, de))));
    de = fmaf(dt[4],w1.x, fmaf(dt[5],w1.y, fmaf(dt[6],w1.z, fmaf(dt[7],w1.w, de))));
    de = fmaf(dt[8],w2.x, fmaf(dt[9],w2.y, fmaf(dt[10],w2.z, fmaf(dt[11],w2.w, de))));
    de = fmaf(dt[12],w3.x, fmaf(dt[13],w3.y, fmaf(dt[14],w3.z, fmaf(dt[15],w3.w, de))));
    de = softplus_fast(de);
    packX[i] = (unsigned)f2bf(xc) | ((unsigned)f2bf(de) << 16);
  }

  // ---- phase 2: local scan (h from 0) with C-apply; write pack (y0,de) ----
  const float* Alog = dir ? Alogb : Alogf;
  float A[NST];
  bool fast = true;
  #pragma unroll
  for (int n = 0; n < NST; n++){
    A[n] = -__expf(Alog[d*NST + n]);
    fast = fast && (fabsf(A[n] + (float)(n+1)) < 1e-3f);
  }
  float h[NST];
  #pragma unroll
  for (int n = 0; n < NST; n++) h[n] = 0.f;
  float S = 0.f;

  unsigned int* xout = xde + ((size_t)(dir*BB + b)*LL + s0)*DD + d;

  if (fast){
    #pragma unroll
    for (int t = 0; t < CLEN; t++){
      unsigned pk = packX[t];
      float xc = bf2f((unsigned short)(pk & 0xffffu));
      float de = bf2f((unsigned short)(pk >> 16));
      S += de;
      float dux = de * xc;
      const float* Bv = &sB[t][0];
      const float* Cv = &sC[t][0];
      float e1 = __expf(-de);
      float dA = e1;
      float acc = xc * Dd;
      h[0] = fmaf(dA, h[0], dux*Bv[0]); acc = fmaf(h[0], Cv[0], acc); dA *= e1;
      h[1] = fmaf(dA, h[1], dux*Bv[1]); acc = fmaf(h[1], Cv[1], acc); dA *= e1;
      h[2] = fmaf(dA, h[2], dux*Bv[2]); acc = fmaf(h[2], Cv[2], acc); dA *= e1;
      h[3] = fmaf(dA, h[3], dux*Bv[3]); acc = fmaf(h[3], Cv[3], acc); dA *= e1;
      h[4] = fmaf(dA, h[4], dux*Bv[4]); acc = fmaf(h[4], Cv[4], acc); dA *= e1;
      h[5] = fmaf(dA, h[5], dux*Bv[5]); acc = fmaf(h[5], Cv[5], acc); dA *= e1;
      h[6] = fmaf(dA, h[6], dux*Bv[6]); acc = fmaf(h[6], Cv[6], acc); dA *= e1;
      h[7] = fmaf(dA, h[7], dux*Bv[7]); acc = fmaf(h[7], Cv[7], acc);
      xout[(size_t)t*DD] = (pk & 0xffff0000u) | (unsigned)f2bf(acc);
    }
  } else {
    #pragma unroll
    for (int t = 0; t < CLEN; t++){
      unsigned pk = packX[t];
      float xc = bf2f((unsigned short)(pk & 0xffffu));
      float de = bf2f((unsigned short)(pk >> 16));
      S += de;
      float dux = de * xc;
      const float* Bv = &sB[t][0];
      const float* Cv = &sC[t][0];
      float acc = xc * Dd;
      #pragma unroll
      for (int n = 0; n < NST; n++){
        h[n] = fmaf(__expf(de*A[n]), h[n], dux*Bv[n]);
        acc = fmaf(h[n], Cv[n], acc);
      }
      xout[(size_t)t*DD] = (pk & 0xffff0000u) | (unsigned)f2bf(acc);
    }
  }

  size_t ob = ((((size_t)dir*CH + chunk)*BB + b)*DD + d)*NST;
  float4 h0v, h1v;
  h0v.x=h[0]; h0v.y=h[1]; h0v.z=h[2]; h0v.w=h[3];
  h1v.x=h[4]; h1v.y=h[5]; h1v.z=h[6]; h1v.w=h[7];
  *(float4*)&Hout[ob]   = h0v; *(float4*)&Hout[ob+4] = h1v;
  Sp[((size_t)(dir*CH + chunk)*BB + b)*DD + d] = S;
}

// Phase 2: chunk-carry scan, 2-level. Block = (dir,b,d) -> 2048 one-wave blocks.
__global__ __launch_bounds__(64) void scan_p2(
    const float* __restrict__ Sp, float* H,
    const float* __restrict__ Alogf, const float* __restrict__ Alogb)
{
  const int SEGC = CH/8;    // 32 chunks per segment
  int blk = blockIdx.x;
  int d   = blk & (DD-1);
  int b   = (blk >> 8) & (BB-1);
  int dir = blk >> 10;
  int t   = threadIdx.x;
  int seg = t >> 3, n = t & 7;
  float A = -__expf((dir ? Alogb : Alogf)[d*NST + n]);

  const size_t sstr = (size_t)BB*DD;          // per-chunk stride in Sp
  const size_t hstr = (size_t)BB*DD*NST;      // per-chunk stride in H
  size_t sb = (size_t)dir*CH*sstr + (size_t)b*DD + d;
  size_t hb = (size_t)dir*CH*hstr + ((size_t)b*DD + d)*NST + n;
  int c0 = seg*SEGC;

  float pv[SEGC], hv[SEGC];
  #pragma unroll
  for (int k = 0; k < SEGC; k++){
    pv[k] = Sp[sb + (size_t)(c0+k)*sstr];
    hv[k] = H [hb + (size_t)(c0+k)*hstr];
  }
  float h = 0.f, Ss = 0.f;
  #pragma unroll
  for (int k = 0; k < SEGC; k++){
    Ss += pv[k];
    pv[k] = __expf(pv[k]*A);
    h = fmaf(pv[k], h, hv[k]);
  }
  float pi = __expf(Ss*A), hi = h;
  #pragma unroll
  for (int off = 8; off < 64; off <<= 1){
    float hprev = __shfl_up(hi, off, 64);
    float pprev = __shfl_up(pi, off, 64);
    if (t >= off){ hi = fmaf(pi, hprev, hi); pi *= pprev; }
  }
  float hin = __shfl_up(hi, 8, 64);
  h = (seg == 0) ? 0.f : hin;
  #pragma unroll
  for (int k = 0; k < SEGC; k++){
    size_t idx = hb + (size_t)(c0+k)*hstr;
    H[idx] = h;
    h = fmaf(pv[k], h, hv[k]);
  }
}

// =================== Back: correction + combine + rmsnorm + gate ==================
// Serial q*=E chain (round-2 version; the E-tree variant regressed via VGPR).
__global__ __launch_bounds__(256) void back_kernel(
    const unsigned int* __restrict__ xde,
    const float* __restrict__ xd,
    const float* __restrict__ Alogf, const float* __restrict__ Alogb,
    const float* __restrict__ Hin,
    const unsigned short* __restrict__ xz,
    const float* __restrict__ wn,
    unsigned short* __restrict__ outb)
{
  int c  = blockIdx.x, b = blockIdx.y;
  int cbk = CH-1-c;
  int d  = threadIdx.x;
  int T0 = c*CLEN;          // token base (fwd storage base)
  int Pb = cbk*CLEN;        // bwd storage base; storage Pb+k <-> token T0+15-k

  __shared__ float sCf[CLEN][8], sCb[CLEN][8];  // 1 KB
  __shared__ float red[CLEN][4];
  __shared__ float sscale[CLEN];
  {
    int k  = threadIdx.x & 7;
    int lt = (threadIdx.x >> 3) & 15;
    if (threadIdx.x < 128)
      sCf[lt][k] = xd[((size_t)b*LL + T0 + lt)*64 + 24 + k];
    else
      sCb[lt][k] = xd[((size_t)b*LL + (T0 + 15 - lt))*64 + 56 + k];
  }
  __syncthreads();

  float Af[NST], Ab[NST];
  bool fast = true;
  #pragma unroll
  for (int n = 0; n < NST; n++){
    Af[n] = -__expf(Alogf[d*NST + n]);
    Ab[n] = -__expf(Alogb[d*NST + n]);
    fast = fast && (fabsf(Af[n] + (float)(n+1)) < 1e-3f)
                && (fabsf(Ab[n] + (float)(n+1)) < 1e-3f);
  }

  float vf[CLEN];

  // ---- forward correction ----
  {
    float hn[NST];
    size_t ib = (((size_t)c*BB + b)*DD + d)*NST;                 // dir=0
    float4 a0 = *(const float4*)&Hin[ib];
    float4 a1 = *(const float4*)&Hin[ib+4];
    hn[0]=a0.x; hn[1]=a0.y; hn[2]=a0.z; hn[3]=a0.w;
    hn[4]=a1.x; hn[5]=a1.y; hn[6]=a1.z; hn[7]=a1.w;
    const unsigned int* p = xde + ((size_t)b*LL + T0)*DD + d;    // dir=0 plane
    unsigned int pk[CLEN];
    #pragma unroll
    for (int t = 0; t < CLEN; t++) pk[t] = p[(size_t)t*DD];
    float S = 0.f;
    if (fast){
      #pragma unroll
      for (int t = 0; t < CLEN; t++){
        float y0 = bf2f((unsigned short)(pk[t] & 0xffffu));
        float de = bf2f((unsigned short)(pk[t] >> 16));
        S += de;
        float E = __expf(-S);
        float q = E;
        float corr = q * (hn[0]*sCf[t][0]);
        q *= E; corr = fmaf(q, hn[1]*sCf[t][1], corr);
        q *= E; corr = fmaf(q, hn[2]*sCf[t][2], corr);
        q *= E; corr = fmaf(q, hn[3]*sCf[t][3], corr);
        q *= E; corr = fmaf(q, hn[4]*sCf[t][4], corr);
        q *= E; corr = fmaf(q, hn[5]*sCf[t][5], corr);
        q *= E; corr = fmaf(q, hn[6]*sCf[t][6], corr);
        q *= E; corr = fmaf(q, hn[7]*sCf[t][7], corr);
        vf[t] = y0 + corr;
      }
    } else {
      #pragma unroll
      for (int t = 0; t < CLEN; t++){
        float y0 = bf2f((unsigned short)(pk[t] & 0xffffu));
        float de = bf2f((unsigned short)(pk[t] >> 16));
        S += de;
        float corr = 0.f;
        #pragma unroll
        for (int n = 0; n < NST; n++)
          corr = fmaf(__expf(S*Af[n]), hn[n]*sCf[t][n], corr);
        vf[t] = y0 + corr;
      }
    }
  }

  // ---- backward correction, merged into vf (token j pairs with bwd k=15-j) ----
  {
    float hn[NST];
    size_t ib = ((((size_t)CH + cbk)*BB + b)*DD + d)*NST;        // dir=1
    float4 a0 = *(const float4*)&Hin[ib];
    float4 a1 = *(const float4*)&Hin[ib+4];
    hn[0]=a0.x; hn[1]=a0.y; hn[2]=a0.z; hn[3]=a0.w;
    hn[4]=a1.x; hn[5]=a1.y; hn[6]=a1.z; hn[7]=a1.w;
    const unsigned int* p = xde + ((size_t)(BB + b)*LL + Pb)*DD + d;  // dir=1 plane
    unsigned int pk[CLEN];
    #pragma unroll
    for (int t = 0; t < CLEN; t++) pk[t] = p[(size_t)t*DD];
    float S = 0.f;
    if (fast){
      #pragma unroll
      for (int t = 0; t < CLEN; t++){
        float y0 = bf2f((unsigned short)(pk[t] & 0xffffu));
        float de = bf2f((unsigned short)(pk[t] >> 16));
        S += de;
        float E = __expf(-S);
        float q = E;
        float corr = q * (hn[0]*sCb[t][0]);
        q *= E; corr = fmaf(q, hn[1]*sCb[t][1], corr);
        q *= E; corr = fmaf(q, hn[2]*sCb[t][2], corr);
        q *= E; corr = fmaf(q, hn[3]*sCb[t][3], corr);
        q *= E; corr = fmaf(q, hn[4]*sCb[t][4], corr);
        q *= E; corr = fmaf(q, hn[5]*sCb[t][5], corr);
        q *= E; corr = fmaf(q, hn[6]*sCb[t][6], corr);
        q *= E; corr = fmaf(q, hn[7]*sCb[t][7], corr);
        int j = 15 - t;
        vf[j] = 0.5f*(vf[j] + y0 + corr);
      }
    } else {
      #pragma unroll
      for (int t = 0; t < CLEN; t++){
        float y0 = bf2f((unsigned short)(pk[t] & 0xffffu));
        float de = bf2f((unsigned short)(pk[t] >> 16));
        S += de;
        float corr = 0.f;
        #pragma unroll
        for (int n = 0; n < NST; n++)
          corr = fmaf(__expf(S*Ab[n]), hn[n]*sCb[t][n], corr);
        int j = 15 - t;
        vf[j] = 0.5f*(vf[j] + y0 + corr);
      }
    }
  }

  // ---- per-token RMS reduce over d ----
  int wave = d >> 6, lane = d & 63;
  #pragma unroll
  for (int j = 0; j < CLEN; j++){
    float s = vf[j]*vf[j];
    #pragma unroll
    for (int m = 1; m < 64; m <<= 1) s += __shfl_xor(s, m, 64);
    if (lane == 0) red[j][wave] = s;
  }
  __syncthreads();
  if (d < CLEN){
    float s = red[d][0] + red[d][1] + red[d][2] + red[d][3];
    sscale[d] = 1.f / (sqrtf(s)*(1.f/16.f) + 1e-6f);
  }
  __syncthreads();

  float wd = wn[d];
  #pragma unroll
  for (int j = 0; j < CLEN; j++){
    size_t tok = (size_t)b*LL + T0 + j;
    float z = bf2f(xz[tok*XZS + 256 + d]);
    outb[tok*DD + d] = f2bf(vf[j]*sscale[j]*wd*siluf(z));
  }
}

// ---------------- FF depthwise conv k=3 pad(1,1) + SiLU -> bf16 ------------------
__global__ __launch_bounds__(256) void dwconv3_kernel(
    const float* __restrict__ m, const float* __restrict__ w,
    const float* __restrict__ bi, unsigned short* __restrict__ o)
{
  size_t gid = (size_t)blockIdx.x*256 + threadIdx.x;  // over BL*HID
  int c = (int)(gid % HID);
  int tok = (int)(gid / HID);
  int b = tok / LL, t = tok % LL;
  float acc = bi[c];
  #pragma unroll
  for (int k = 0; k < 3; k++){
    int tt = t - 1 + k;
    if (tt >= 0 && tt < LL)
      acc = fmaf(w[c*3 + k], m[((size_t)b*LL + tt)*HID + c], acc);
  }
  o[gid] = f2bf(siluf(acc));
}

extern "C" void kernel_launch(void* const* d_in, const int* in_sizes, int n_in,
                              void* d_out, int out_size, void* d_ws, size_t ws_size,
                              hipStream_t stream)
{
  const float* x0        = (const float*)d_in[0];
  const float* x1        = (const float*)d_in[1];
  const float* w_norm0   = (const float*)d_in[2];
  const float* w_norm1   = (const float*)d_in[3];
  const float* in_proj_w = (const float*)d_in[4];
  const float* conv_w_f  = (const float*)d_in[5];
  const float* conv_b_f  = (const float*)d_in[6];
  const float* xproj_w_f = (const float*)d_in[7];
  const float* dtproj_w_f= (const float*)d_in[8];
  const float* dtproj_b_f= (const float*)d_in[9];
  const float* A_log_f   = (const float*)d_in[10];
  const float* D_f       = (const float*)d_in[11];
  const float* conv_w_bw = (const float*)d_in[12];
  const float* conv_b_bw = (const float*)d_in[13];
  const float* xproj_w_bw= (const float*)d_in[14];
  const float* dtproj_w_bw=(const float*)d_in[15];
  const float* dtproj_b_bw=(const float*)d_in[16];
  const float* A_log_bw  = (const float*)d_in[17];
  const float* D_bw      = (const float*)d_in[18];
  const float* norm_y_w  = (const float*)d_in[19];
  const float* out_proj_w= (const float*)d_in[20];
  const float* fc1_w     = (const float*)d_in[21];
  const float* dw_w      = (const float*)d_in[22];
  const float* dw_b      = (const float*)d_in[23];
  const float* fc2_w     = (const float*)d_in[24];
  float* out = (float*)d_out;
  float* ws  = (float*)d_ws;

  // region map (floats, BLD each), lifetime-reused
  float* r0 = ws + 0*BLD;   // h0b (bf16) -> ycomb_b (bf16)
  float* r1 = ws + 1*BLD;   // h1b (bf16)
  float* r2 = ws + 2*BLD;   // xz_b (bf16, BL x 512 = full region)
  float* r3 = ws + 3*BLD;   // xd (fp32 BLx64, 4MB) -- live through back_kernel
  float* r4 = ws + 4*BLD;   // xde pack (y0,de) (uint32, spans r4+r5) -> m1 (fp32)
  float* r5 = ws + 5*BLD;   //                                       -> m2b (bf16)
  float* r6 = ws + 6*BLD;   // wbuf1 (bf16 in_proj) -> Hout (= Hin, in-place p2)
  float* r7 = ws + 7*BLD;   // wbuf2 (bf16 weights) + xb (bf16) + S-plane (tail)

  unsigned short* h0b   = (unsigned short*)r0;
  unsigned short* h1b   = (unsigned short*)r1;
  unsigned short* xz_b  = (unsigned short*)r2;   // BL x XZS
  float*          xd    = r3;                    // BL x 64 fp32
  unsigned int*   xde   = (unsigned int*)r4;     // 2*BLD dwords = r4+r5
  unsigned short* wbuf1 = (unsigned short*)r6;   // 131072 (512x256)
  float* Hout = r6;                              // 2*CH*BB*DD*NST = BLD floats
  float* Hin  = Hout;                            // p2 rewrites in place
  const size_t SPLANE = (size_t)2*CH*BB*DD;      // 524288 floats (2 MB)
  float* Sp   = r7 + (BLD - SPLANE);             // tail of r7 (disjoint from wbuf2/xb)
  unsigned short* ycomb_b = (unsigned short*)r0; // r0 free after gemm xz (h0b dead)
  unsigned short* wbuf2   = (unsigned short*)r7;
  unsigned short* wb_xp   = wbuf2;               // 16384  (64x256)
  unsigned short* wb_out  = wbuf2 + 16384;       // 65536
  unsigned short* wb_fc1  = wbuf2 + 81920;       // 32768
  unsigned short* wb_fc2  = wbuf2 + 114688;      // 32768
  unsigned short* xb      = wbuf2 + 147456;      // BLD bf16
  float*          m1      = r4;
  unsigned short* m2b     = (unsigned short*)r5;

  // 0. weight conversions
  cvt1_kernel<<<dim3(512), 256, 0, stream>>>(in_proj_w, wbuf1, 131072);
  cvt5_kernel<<<dim3(576), 256, 0, stream>>>(
      xproj_w_f, xproj_w_bw, out_proj_w, fc1_w, fc2_w, wbuf2);

  // 1. RMSNorm x0 -> h0b, x1 -> h1b (both bf16)
  rms_kernel<<<dim3(BL,2), 64, 0, stream>>>(x0, w_norm0, h0b, x1, w_norm1, h1b);

  // 2. xz = h0 @ in_proj.T -> xz_b (bf16, 128x128 tiles, N=512)
  gemm128<3><<<dim3(BL/128, 4), 256, 0, stream>>>(
      h0b, wbuf1, nullptr, nullptr, xz_b, XZS, 256);

  // 3. merged xproj (N=64): xd[t][0..31]=fwd dt/B/C, [32..63]=bwd
  gemm_mfma<0><<<dim3(BL/64, 1), 256, 0, stream>>>(
      h1b, wb_xp, xd, nullptr, nullptr, BL, 64, 256);

  // 4. front: conv+silu+delta + local scan w/ C-apply -> pack(y0,de), S, Hout
  front_kernel<<<dim3(CH, BB, 2), 256, 0, stream>>>(
      xz_b, xd, conv_w_f, conv_b_f, conv_w_bw, conv_b_bw,
      dtproj_w_f, dtproj_b_f, dtproj_w_bw, dtproj_b_bw,
      A_log_f, A_log_bw, D_f, D_bw, xde, Sp, Hout);

  // 5. chunk-carry scan (2-level, in-place Hout->Hin)
  scan_p2<<<dim3(2*BB*DD), 64, 0, stream>>>(Sp, Hout, A_log_f, A_log_bw);

  // 6. fused correction + combine + rmsnorm + gate -> ycomb_b (r0)
  back_kernel<<<dim3(CH, BB), 256, 0, stream>>>(
      xde, xd, A_log_f, A_log_bw, Hin, xz_b, norm_y_w, ycomb_b);

  // 7. x = y @ out_proj.T + residual(x0) -> d_out (fp32) + xb (bf16), N=256
  gemm128<1><<<dim3(BL/128, 2), 256, 0, stream>>>(
      ycomb_b, wb_out, out, x0, xb, 256, 256);

  // 8. m1 = x @ fc1.T (fp32; overwrites dead xde), N=128
  gemm128<0><<<dim3(BL/128, 1), 256, 0, stream>>>(
      xb, wb_fc1, m1, nullptr, nullptr, 128, 256);

  // 9. m2 = silu(dwconv3(m1)) -> bf16
  dwconv3_kernel<<<dim3((BL*HID)/256), 256, 0, stream>>>(m1, dw_w, dw_b, m2b);

  // 10. out = x + m2 @ fc2.T, N=256, K=128
  gemm128<2><<<dim3(BL/128, 2), 256, 0, stream>>>(
      m2b, wb_fc2, out, out, nullptr, 256, 128);
}

// Round 5
// 260.985 us; speedup vs baseline: 1.0431x; 1.0223x over previous
//
#include <hip/hip_runtime.h>
#include <math.h>
#include <cstddef>

#define BB 4
#define LL 4096
#define DD 256
#define NST 8
#define RANK 16
#define HID 128
#define BL (BB*LL)          // 16384
#define BLD ((size_t)BL*DD) // 4194304
#define CH 256              // scan chunks
#define CLEN 16             // steps per chunk (CH*CLEN == LL)
#define XZS 512             // xz row stride (xin cols 0..255, z cols 256..511)

typedef __bf16 bf16x8 __attribute__((ext_vector_type(8)));
typedef float  f32x4  __attribute__((ext_vector_type(4)));

__device__ __forceinline__ float siluf(float x){ return x / (1.f + __expf(-x)); }
__device__ __forceinline__ float softplus_fast(float x){
  float r = __logf(1.f + __expf(x));
  return x > 15.f ? x : r;
}
// fp32 -> bf16 bits, round-to-nearest-even
__device__ __forceinline__ unsigned short f2bf(float x){
  union { float f; unsigned u; } v; v.f = x;
  unsigned r = v.u + 0x7fffu + ((v.u >> 16) & 1u);
  return (unsigned short)(r >> 16);
}
__device__ __forceinline__ float bf2f(unsigned short u){
  union { unsigned u32; float f; } c; c.u32 = ((unsigned)u) << 16;
  return c.f;
}

// ---------------- RMSNorm: both streams -> bf16 ----------------------------------
__global__ __launch_bounds__(64) void rms_kernel(
    const float* __restrict__ x0, const float* __restrict__ w0, unsigned short* __restrict__ o0b,
    const float* __restrict__ x1, const float* __restrict__ w1, unsigned short* __restrict__ o1b)
{
  const float* x; const float* w; unsigned short* o;
  if (blockIdx.y == 0){ x = x0; w = w0; o = o0b; } else { x = x1; w = w1; o = o1b; }
  size_t tok = blockIdx.x;
  int lane = threadIdx.x;
  float4 v = ((const float4*)(x + tok*DD))[lane];
  float s = v.x*v.x + v.y*v.y + v.z*v.z + v.w*v.w;
  #pragma unroll
  for (int m = 1; m < 64; m <<= 1) s += __shfl_xor(s, m, 64);
  float scale = 1.f / (sqrtf(s) * (1.f/16.f) + 1e-6f);
  float4 wv = ((const float4*)w)[lane];
  ushort4 r;
  r.x = f2bf(v.x*scale*wv.x); r.y = f2bf(v.y*scale*wv.y);
  r.z = f2bf(v.z*scale*wv.z); r.w = f2bf(v.w*scale*wv.w);
  ((ushort4*)(o + tok*DD))[lane] = r;
}

// ---------------- merged weight fp32->bf16 conversion ----------------------------
// d1: in_proj (131072). d2: xproj_f(8192)|xproj_bw(8192)|out_proj(65536)|
// fc1(32768)|fc2(32768) = 147456. One kernel, 1088 blocks.
__global__ __launch_bounds__(256) void cvt_kernel(
    const float* __restrict__ sA,
    const float* __restrict__ s0, const float* __restrict__ s1,
    const float* __restrict__ s2, const float* __restrict__ s3,
    const float* __restrict__ s4,
    unsigned short* __restrict__ d1, unsigned short* __restrict__ d2)
{
  int i = blockIdx.x*256 + threadIdx.x;   // 0..278527
  if (i >= 278528) return;
  if (i < 131072){ d1[i] = f2bf(sA[i]); return; }
  int j = i - 131072;
  float v;
  if (j < 8192)        v = s0[j];
  else if (j < 16384)  v = s1[j - 8192];
  else if (j < 81920)  v = s2[j - 16384];
  else if (j < 114688) v = s3[j - 81920];
  else                 v = s4[j - 114688];
  d2[j] = f2bf(v);
}

// ---------------- bf16 MFMA GEMM, 64x64 tile, BK=64: C = A @ Bw^T (+ epilogue) ---
// EPI: 0 = C=acc ; 1 = C=acc+Add & Cb=bf16(C) ; 2 = C=acc+Add ; 3 = Cb=bf16(acc)
// ldc = row stride of C/Cb/Add. Empirically beats a 128x128 tile at these
// small-K (256/128) skinny-N shapes (r4: 128-tile cost +27us across 4 dispatches
// -- prologue/epilogue dominate at 2-4 K-iters, fewer blocks to overlap).
template<int EPI>
__global__ __launch_bounds__(256) void gemm_mfma(
    const unsigned short* __restrict__ A, const unsigned short* __restrict__ Bw,
    float* __restrict__ C, const float* __restrict__ Add,
    unsigned short* __restrict__ Cb, int M, int ldc, int K)
{
  constexpr int BK = 64, PAD = 8;
  __shared__ __align__(16) unsigned short As[64][BK+PAD];
  __shared__ __align__(16) unsigned short Bs[64][BK+PAD];
  int tid  = threadIdx.x;
  int row0 = blockIdx.x * 64;
  int col0 = blockIdx.y * 64;
  int wave = tid >> 6, lane = tid & 63;
  int wm = (wave >> 1) * 32, wn = (wave & 1) * 32;
  int lm = lane & 15, kq = lane >> 4;
  int sr = tid >> 2, sc16 = (tid & 3) * 16;

  f32x4 acc[2][2];
  #pragma unroll
  for (int i = 0; i < 2; i++)
    #pragma unroll
    for (int j = 0; j < 2; j++) acc[i][j] = (f32x4){0.f,0.f,0.f,0.f};

  for (int k0 = 0; k0 < K; k0 += BK){
    const unsigned short* ap = &A [(size_t)(row0 + sr)*K + k0 + sc16];
    const unsigned short* bp = &Bw[(size_t)(col0 + sr)*K + k0 + sc16];
    *(int4*)&As[sr][sc16]   = *(const int4*)ap;
    *(int4*)&As[sr][sc16+8] = *(const int4*)(ap + 8);
    *(int4*)&Bs[sr][sc16]   = *(const int4*)bp;
    *(int4*)&Bs[sr][sc16+8] = *(const int4*)(bp + 8);
    __syncthreads();
    #pragma unroll
    for (int ks = 0; ks < 2; ks++){
      bf16x8 af[2], bfv[2];
      #pragma unroll
      for (int i = 0; i < 2; i++) af[i]  = *(const bf16x8*)&As[wm + i*16 + lm][ks*32 + kq*8];
      #pragma unroll
      for (int j = 0; j < 2; j++) bfv[j] = *(const bf16x8*)&Bs[wn + j*16 + lm][ks*32 + kq*8];
      #pragma unroll
      for (int i = 0; i < 2; i++)
        #pragma unroll
        for (int j = 0; j < 2; j++)
          acc[i][j] = __builtin_amdgcn_mfma_f32_16x16x32_bf16(af[i], bfv[j], acc[i][j], 0, 0, 0);
    }
    __syncthreads();
  }

  // C/D layout: col = lane&15, row = (lane>>4)*4 + reg   [m89-verified]
  #pragma unroll
  for (int i = 0; i < 2; i++){
    int rbase = row0 + wm + i*16 + kq*4;
    #pragma unroll
    for (int j = 0; j < 2; j++){
      int col = col0 + wn + j*16 + lm;
      #pragma unroll
      for (int r = 0; r < 4; r++){
        size_t idx = (size_t)(rbase + r)*ldc + col;
        float v = acc[i][j][r];
        if constexpr (EPI == 1 || EPI == 2) v += Add[idx];
        if constexpr (EPI != 3) C[idx] = v;
        if constexpr (EPI == 1 || EPI == 3) Cb[idx] = f2bf(v);
      }
    }
  }
}

// =================== Front: conv+silu+delta + local scan w/ C-apply ==============
// MEASURED-BEST STRUCTURE (43.4us, VGPR 80, occ 24%): split-phase (phase 1 = all
// 16 steps' conv/dt/softplus with full ILP into packX; phase 2 = serial scan with
// the dA*=e1 chain). Known-bad variants: merged single loop (67us, kills
// pipelining); e1..e8 power tree (54us, VGPR 88 -> occupancy drop). Do not touch.
__global__ __launch_bounds__(256) void front_kernel(
    const unsigned short* __restrict__ xz,
    const float* __restrict__ xd,
    const float* __restrict__ cwf, const float* __restrict__ cbf,
    const float* __restrict__ cwb, const float* __restrict__ cbb,
    const float* __restrict__ dtwf, const float* __restrict__ dtbf,
    const float* __restrict__ dtwb, const float* __restrict__ dtbb,
    const float* __restrict__ Alogf, const float* __restrict__ Alogb,
    const float* __restrict__ Dfp, const float* __restrict__ Dbp,
    unsigned int* __restrict__ xde,
    float* __restrict__ Sp, float* __restrict__ Hout)
{
  int chunk = blockIdx.x, b = blockIdx.y, dir = blockIdx.z;
  int s0 = chunk*CLEN;
  int d  = threadIdx.x;

  __shared__ float sdt[CLEN][16];   // 1 KB
  __shared__ float sB [CLEN][8];    // 0.5 KB
  __shared__ float sC [CLEN][8];    // 0.5 KB
  #pragma unroll
  for (int e = threadIdx.x; e < CLEN*32; e += 256){
    int lt = e >> 5, col = e & 31;
    int pos = s0 + lt;
    int row = dir ? (LL-1-pos) : pos;
    float v = xd[((size_t)b*LL + row)*64 + dir*32 + col];
    if (col < 16)      sdt[lt][col]    = v;
    else if (col < 24) sB [lt][col-16] = v;
    else               sC [lt][col-24] = v;
  }
  __syncthreads();

  float4 cw = ((const float4*)(dir ? cwb : cwf))[d];
  float cb  = (dir ? cbb : cbf)[d];
  const float* dtw = (dir ? dtwb : dtwf) + d*RANK;
  float4 w0 = ((const float4*)dtw)[0], w1 = ((const float4*)dtw)[1];
  float4 w2 = ((const float4*)dtw)[2], w3 = ((const float4*)dtw)[3];
  float dtb = (dir ? dtbb : dtbf)[d];
  float Dd  = (dir ? Dbp : Dfp)[d];

  const unsigned short* xp = xz + (size_t)b*LL*XZS + d;
  #define LDX(pos) ((pos) >= 0 ? bf2f(xp[(size_t)(dir ? (LL-1-(pos)) : (pos))*XZS]) : 0.f)

  // ---- phase 1: conv + silu + delta, packed into regs (full ILP) ----
  float xv[CLEN+3];
  xv[0] = LDX(s0-3); xv[1] = LDX(s0-2); xv[2] = LDX(s0-1);
  #pragma unroll
  for (int i = 0; i < CLEN; i++) xv[3+i] = LDX(s0+i);
  #undef LDX

  unsigned packX[CLEN];
  #pragma unroll
  for (int i = 0; i < CLEN; i++){
    float xc = cb;
    xc = fmaf(cw.x, xv[i],   xc); xc = fmaf(cw.y, xv[i+1], xc);
    xc = fmaf(cw.z, xv[i+2], xc); xc = fmaf(cw.w, xv[i+3], xc);
    xc = siluf(xc);
    const float* dt = &sdt[i][0];
    float de = dtb;
    de = fmaf(dt[0],w0.x, fmaf(dt[1],w0.y, fmaf(dt[2],w0.z, fmaf(dt[3],w0.w, de))));
    de = fmaf(dt[4],w1.x, fmaf(dt[5],w1.y, fmaf(dt[6],w1.z, fmaf(dt[7],w1.w, de))));
    de = fmaf(dt[8],w2.x, fmaf(dt[9],w2.y, fmaf(dt[10],w2.z, fmaf(dt[11],w2.w, de))));
    de = fmaf(dt[12],w3.x, fmaf(dt[13],w3.y, fmaf(dt[14],w3.z, fmaf(dt[15],w3.w, de))));
    de = softplus_fast(de);
    packX[i] = (unsigned)f2bf(xc) | ((unsigned)f2bf(de) << 16);
  }

  // ---- phase 2: local scan (h from 0) with C-apply; write pack (y0,de) ----
  const float* Alog = dir ? Alogb : Alogf;
  float A[NST];
  bool fast = true;
  #pragma unroll
  for (int n = 0; n < NST; n++){
    A[n] = -__expf(Alog[d*NST + n]);
    fast = fast && (fabsf(A[n] + (float)(n+1)) < 1e-3f);
  }
  float h[NST];
  #pragma unroll
  for (int n = 0; n < NST; n++) h[n] = 0.f;
  float S = 0.f;

  unsigned int* xout = xde + ((size_t)(dir*BB + b)*LL + s0)*DD + d;

  if (fast){
    #pragma unroll
    for (int t = 0; t < CLEN; t++){
      unsigned pk = packX[t];
      float xc = bf2f((unsigned short)(pk & 0xffffu));
      float de = bf2f((unsigned short)(pk >> 16));
      S += de;
      float dux = de * xc;
      const float* Bv = &sB[t][0];
      const float* Cv = &sC[t][0];
      float e1 = __expf(-de);
      float dA = e1;
      float acc = xc * Dd;
      h[0] = fmaf(dA, h[0], dux*Bv[0]); acc = fmaf(h[0], Cv[0], acc); dA *= e1;
      h[1] = fmaf(dA, h[1], dux*Bv[1]); acc = fmaf(h[1], Cv[1], acc); dA *= e1;
      h[2] = fmaf(dA, h[2], dux*Bv[2]); acc = fmaf(h[2], Cv[2], acc); dA *= e1;
      h[3] = fmaf(dA, h[3], dux*Bv[3]); acc = fmaf(h[3], Cv[3], acc); dA *= e1;
      h[4] = fmaf(dA, h[4], dux*Bv[4]); acc = fmaf(h[4], Cv[4], acc); dA *= e1;
      h[5] = fmaf(dA, h[5], dux*Bv[5]); acc = fmaf(h[5], Cv[5], acc); dA *= e1;
      h[6] = fmaf(dA, h[6], dux*Bv[6]); acc = fmaf(h[6], Cv[6], acc); dA *= e1;
      h[7] = fmaf(dA, h[7], dux*Bv[7]); acc = fmaf(h[7], Cv[7], acc);
      xout[(size_t)t*DD] = (pk & 0xffff0000u) | (unsigned)f2bf(acc);
    }
  } else {
    #pragma unroll
    for (int t = 0; t < CLEN; t++){
      unsigned pk = packX[t];
      float xc = bf2f((unsigned short)(pk & 0xffffu));
      float de = bf2f((unsigned short)(pk >> 16));
      S += de;
      float dux = de * xc;
      const float* Bv = &sB[t][0];
      const float* Cv = &sC[t][0];
      float acc = xc * Dd;
      #pragma unroll
      for (int n = 0; n < NST; n++){
        h[n] = fmaf(__expf(de*A[n]), h[n], dux*Bv[n]);
        acc = fmaf(h[n], Cv[n], acc);
      }
      xout[(size_t)t*DD] = (pk & 0xffff0000u) | (unsigned)f2bf(acc);
    }
  }

  size_t ob = ((((size_t)dir*CH + chunk)*BB + b)*DD + d)*NST;
  float4 h0v, h1v;
  h0v.x=h[0]; h0v.y=h[1]; h0v.z=h[2]; h0v.w=h[3];
  h1v.x=h[4]; h1v.y=h[5]; h1v.z=h[6]; h1v.w=h[7];
  *(float4*)&Hout[ob]   = h0v; *(float4*)&Hout[ob+4] = h1v;
  Sp[((size_t)(dir*CH + chunk)*BB + b)*DD + d] = S;
}

// Phase 2: chunk-carry scan, 2-level. Block = (dir,b,d) -> 2048 one-wave blocks.
__global__ __launch_bounds__(64) void scan_p2(
    const float* __restrict__ Sp, float* H,
    const float* __restrict__ Alogf, const float* __restrict__ Alogb)
{
  const int SEGC = CH/8;    // 32 chunks per segment
  int blk = blockIdx.x;
  int d   = blk & (DD-1);
  int b   = (blk >> 8) & (BB-1);
  int dir = blk >> 10;
  int t   = threadIdx.x;
  int seg = t >> 3, n = t & 7;
  float A = -__expf((dir ? Alogb : Alogf)[d*NST + n]);

  const size_t sstr = (size_t)BB*DD;          // per-chunk stride in Sp
  const size_t hstr = (size_t)BB*DD*NST;      // per-chunk stride in H
  size_t sb = (size_t)dir*CH*sstr + (size_t)b*DD + d;
  size_t hb = (size_t)dir*CH*hstr + ((size_t)b*DD + d)*NST + n;
  int c0 = seg*SEGC;

  float pv[SEGC], hv[SEGC];
  #pragma unroll
  for (int k = 0; k < SEGC; k++){
    pv[k] = Sp[sb + (size_t)(c0+k)*sstr];
    hv[k] = H [hb + (size_t)(c0+k)*hstr];
  }
  float h = 0.f, Ss = 0.f;
  #pragma unroll
  for (int k = 0; k < SEGC; k++){
    Ss += pv[k];
    pv[k] = __expf(pv[k]*A);
    h = fmaf(pv[k], h, hv[k]);
  }
  float pi = __expf(Ss*A), hi = h;
  #pragma unroll
  for (int off = 8; off < 64; off <<= 1){
    float hprev = __shfl_up(hi, off, 64);
    float pprev = __shfl_up(pi, off, 64);
    if (t >= off){ hi = fmaf(pi, hprev, hi); pi *= pprev; }
  }
  float hin = __shfl_up(hi, 8, 64);
  h = (seg == 0) ? 0.f : hin;
  #pragma unroll
  for (int k = 0; k < SEGC; k++){
    size_t idx = hb + (size_t)(c0+k)*hstr;
    H[idx] = h;
    h = fmaf(pv[k], h, hv[k]);
  }
}

// =================== Back: correction + combine + rmsnorm + gate ==================
// Serial q*=E chain (measured-best; the E-tree variant regressed via VGPR).
__global__ __launch_bounds__(256) void back_kernel(
    const unsigned int* __restrict__ xde,
    const float* __restrict__ xd,
    const float* __restrict__ Alogf, const float* __restrict__ Alogb,
    const float* __restrict__ Hin,
    const unsigned short* __restrict__ xz,
    const float* __restrict__ wn,
    unsigned short* __restrict__ outb)
{
  int c  = blockIdx.x, b = blockIdx.y;
  int cbk = CH-1-c;
  int d  = threadIdx.x;
  int T0 = c*CLEN;          // token base (fwd storage base)
  int Pb = cbk*CLEN;        // bwd storage base; storage Pb+k <-> token T0+15-k

  __shared__ float sCf[CLEN][8], sCb[CLEN][8];  // 1 KB
  __shared__ float red[CLEN][4];
  __shared__ float sscale[CLEN];
  {
    int k  = threadIdx.x & 7;
    int lt = (threadIdx.x >> 3) & 15;
    if (threadIdx.x < 128)
      sCf[lt][k] = xd[((size_t)b*LL + T0 + lt)*64 + 24 + k];
    else
      sCb[lt][k] = xd[((size_t)b*LL + (T0 + 15 - lt))*64 + 56 + k];
  }
  __syncthreads();

  float Af[NST], Ab[NST];
  bool fast = true;
  #pragma unroll
  for (int n = 0; n < NST; n++){
    Af[n] = -__expf(Alogf[d*NST + n]);
    Ab[n] = -__expf(Alogb[d*NST + n]);
    fast = fast && (fabsf(Af[n] + (float)(n+1)) < 1e-3f)
                && (fabsf(Ab[n] + (float)(n+1)) < 1e-3f);
  }

  float vf[CLEN];

  // ---- forward correction ----
  {
    float hn[NST];
    size_t ib = (((size_t)c*BB + b)*DD + d)*NST;                 // dir=0
    float4 a0 = *(const float4*)&Hin[ib];
    float4 a1 = *(const float4*)&Hin[ib+4];
    hn[0]=a0.x; hn[1]=a0.y; hn[2]=a0.z; hn[3]=a0.w;
    hn[4]=a1.x; hn[5]=a1.y; hn[6]=a1.z; hn[7]=a1.w;
    const unsigned int* p = xde + ((size_t)b*LL + T0)*DD + d;    // dir=0 plane
    unsigned int pk[CLEN];
    #pragma unroll
    for (int t = 0; t < CLEN; t++) pk[t] = p[(size_t)t*DD];
    float S = 0.f;
    if (fast){
      #pragma unroll
      for (int t = 0; t < CLEN; t++){
        float y0 = bf2f((unsigned short)(pk[t] & 0xffffu));
        float de = bf2f((unsigned short)(pk[t] >> 16));
        S += de;
        float E = __expf(-S);
        float q = E;
        float corr = q * (hn[0]*sCf[t][0]);
        q *= E; corr = fmaf(q, hn[1]*sCf[t][1], corr);
        q *= E; corr = fmaf(q, hn[2]*sCf[t][2], corr);
        q *= E; corr = fmaf(q, hn[3]*sCf[t][3], corr);
        q *= E; corr = fmaf(q, hn[4]*sCf[t][4], corr);
        q *= E; corr = fmaf(q, hn[5]*sCf[t][5], corr);
        q *= E; corr = fmaf(q, hn[6]*sCf[t][6], corr);
        q *= E; corr = fmaf(q, hn[7]*sCf[t][7], corr);
        vf[t] = y0 + corr;
      }
    } else {
      #pragma unroll
      for (int t = 0; t < CLEN; t++){
        float y0 = bf2f((unsigned short)(pk[t] & 0xffffu));
        float de = bf2f((unsigned short)(pk[t] >> 16));
        S += de;
        float corr = 0.f;
        #pragma unroll
        for (int n = 0; n < NST; n++)
          corr = fmaf(__expf(S*Af[n]), hn[n]*sCf[t][n], corr);
        vf[t] = y0 + corr;
      }
    }
  }

  // ---- backward correction, merged into vf (token j pairs with bwd k=15-j) ----
  {
    float hn[NST];
    size_t ib = ((((size_t)CH + cbk)*BB + b)*DD + d)*NST;        // dir=1
    float4 a0 = *(const float4*)&Hin[ib];
    float4 a1 = *(const float4*)&Hin[ib+4];
    hn[0]=a0.x; hn[1]=a0.y; hn[2]=a0.z; hn[3]=a0.w;
    hn[4]=a1.x; hn[5]=a1.y; hn[6]=a1.z; hn[7]=a1.w;
    const unsigned int* p = xde + ((size_t)(BB + b)*LL + Pb)*DD + d;  // dir=1 plane
    unsigned int pk[CLEN];
    #pragma unroll
    for (int t = 0; t < CLEN; t++) pk[t] = p[(size_t)t*DD];
    float S = 0.f;
    if (fast){
      #pragma unroll
      for (int t = 0; t < CLEN; t++){
        float y0 = bf2f((unsigned short)(pk[t] & 0xffffu));
        float de = bf2f((unsigned short)(pk[t] >> 16));
        S += de;
        float E = __expf(-S);
        float q = E;
        float corr = q * (hn[0]*sCb[t][0]);
        q *= E; corr = fmaf(q, hn[1]*sCb[t][1], corr);
        q *= E; corr = fmaf(q, hn[2]*sCb[t][2], corr);
        q *= E; corr = fmaf(q, hn[3]*sCb[t][3], corr);
        q *= E; corr = fmaf(q, hn[4]*sCb[t][4], corr);
        q *= E; corr = fmaf(q, hn[5]*sCb[t][5], corr);
        q *= E; corr = fmaf(q, hn[6]*sCb[t][6], corr);
        q *= E; corr = fmaf(q, hn[7]*sCb[t][7], corr);
        int j = 15 - t;
        vf[j] = 0.5f*(vf[j] + y0 + corr);
      }
    } else {
      #pragma unroll
      for (int t = 0; t < CLEN; t++){
        float y0 = bf2f((unsigned short)(pk[t] & 0xffffu));
        float de = bf2f((unsigned short)(pk[t] >> 16));
        S += de;
        float corr = 0.f;
        #pragma unroll
        for (int n = 0; n < NST; n++)
          corr = fmaf(__expf(S*Ab[n]), hn[n]*sCb[t][n], corr);
        int j = 15 - t;
        vf[j] = 0.5f*(vf[j] + y0 + corr);
      }
    }
  }

  // ---- per-token RMS reduce over d ----
  int wave = d >> 6, lane = d & 63;
  #pragma unroll
  for (int j = 0; j < CLEN; j++){
    float s = vf[j]*vf[j];
    #pragma unroll
    for (int m = 1; m < 64; m <<= 1) s += __shfl_xor(s, m, 64);
    if (lane == 0) red[j][wave] = s;
  }
  __syncthreads();
  if (d < CLEN){
    float s = red[d][0] + red[d][1] + red[d][2] + red[d][3];
    sscale[d] = 1.f / (sqrtf(s)*(1.f/16.f) + 1e-6f);
  }
  __syncthreads();

  float wd = wn[d];
  #pragma unroll
  for (int j = 0; j < CLEN; j++){
    size_t tok = (size_t)b*LL + T0 + j;
    float z = bf2f(xz[tok*XZS + 256 + d]);
    outb[tok*DD + d] = f2bf(vf[j]*sscale[j]*wd*siluf(z));
  }
}

// ---------------- FF depthwise conv k=3 pad(1,1) + SiLU -> bf16 ------------------
// 4 channels/thread: float4 loads (16B/lane), ushort4 store.
__global__ __launch_bounds__(256) void dwconv3_kernel(
    const float* __restrict__ m, const float* __restrict__ w,
    const float* __restrict__ bi, unsigned short* __restrict__ o)
{
  size_t gid = (size_t)blockIdx.x*256 + threadIdx.x;  // over BL*HID/4
  int c4  = (int)(gid & 31) * 4;       // HID/4 = 32
  int tok = (int)(gid >> 5);
  int b = tok >> 12, t = tok & (LL-1);
  float4 acc = {bi[c4], bi[c4+1], bi[c4+2], bi[c4+3]};
  #pragma unroll
  for (int k = 0; k < 3; k++){
    int tt = t - 1 + k;
    if (tt >= 0 && tt < LL){
      float4 mv = *(const float4*)&m[((size_t)b*LL + tt)*HID + c4];
      acc.x = fmaf(w[c4*3 + k],       mv.x, acc.x);
      acc.y = fmaf(w[(c4+1)*3 + k],   mv.y, acc.y);
      acc.z = fmaf(w[(c4+2)*3 + k],   mv.z, acc.z);
      acc.w = fmaf(w[(c4+3)*3 + k],   mv.w, acc.w);
    }
  }
  ushort4 r;
  r.x = f2bf(siluf(acc.x)); r.y = f2bf(siluf(acc.y));
  r.z = f2bf(siluf(acc.z)); r.w = f2bf(siluf(acc.w));
  *(ushort4*)&o[gid*4] = r;
}

extern "C" void kernel_launch(void* const* d_in, const int* in_sizes, int n_in,
                              void* d_out, int out_size, void* d_ws, size_t ws_size,
                              hipStream_t stream)
{
  const float* x0        = (const float*)d_in[0];
  const float* x1        = (const float*)d_in[1];
  const float* w_norm0   = (const float*)d_in[2];
  const float* w_norm1   = (const float*)d_in[3];
  const float* in_proj_w = (const float*)d_in[4];
  const float* conv_w_f  = (const float*)d_in[5];
  const float* conv_b_f  = (const float*)d_in[6];
  const float* xproj_w_f = (const float*)d_in[7];
  const float* dtproj_w_f= (const float*)d_in[8];
  const float* dtproj_b_f= (const float*)d_in[9];
  const float* A_log_f   = (const float*)d_in[10];
  const float* D_f       = (const float*)d_in[11];
  const float* conv_w_bw = (const float*)d_in[12];
  const float* conv_b_bw = (const float*)d_in[13];
  const float* xproj_w_bw= (const float*)d_in[14];
  const float* dtproj_w_bw=(const float*)d_in[15];
  const float* dtproj_b_bw=(const float*)d_in[16];
  const float* A_log_bw  = (const float*)d_in[17];
  const float* D_bw      = (const float*)d_in[18];
  const float* norm_y_w  = (const float*)d_in[19];
  const float* out_proj_w= (const float*)d_in[20];
  const float* fc1_w     = (const float*)d_in[21];
  const float* dw_w      = (const float*)d_in[22];
  const float* dw_b      = (const float*)d_in[23];
  const float* fc2_w     = (const float*)d_in[24];
  float* out = (float*)d_out;
  float* ws  = (float*)d_ws;

  // region map (floats, BLD each), lifetime-reused
  float* r0 = ws + 0*BLD;   // h0b (bf16) -> ycomb_b (bf16)
  float* r1 = ws + 1*BLD;   // h1b (bf16)
  float* r2 = ws + 2*BLD;   // xz_b (bf16, BL x 512 = full region)
  float* r3 = ws + 3*BLD;   // xd (fp32 BLx64, 4MB) -- live through back_kernel
  float* r4 = ws + 4*BLD;   // xde pack (y0,de) (uint32, spans r4+r5) -> m1 (fp32)
  float* r5 = ws + 5*BLD;   //                                       -> m2b (bf16)
  float* r6 = ws + 6*BLD;   // wbuf1 (bf16 in_proj) -> Hout (= Hin, in-place p2)
  float* r7 = ws + 7*BLD;   // wbuf2 (bf16 weights) + xb (bf16) + S-plane (tail)

  unsigned short* h0b   = (unsigned short*)r0;
  unsigned short* h1b   = (unsigned short*)r1;
  unsigned short* xz_b  = (unsigned short*)r2;   // BL x XZS
  float*          xd    = r3;                    // BL x 64 fp32
  unsigned int*   xde   = (unsigned int*)r4;     // 2*BLD dwords = r4+r5
  unsigned short* wbuf1 = (unsigned short*)r6;   // 131072 (512x256)
  float* Hout = r6;                              // 2*CH*BB*DD*NST = BLD floats
  float* Hin  = Hout;                            // p2 rewrites in place
  const size_t SPLANE = (size_t)2*CH*BB*DD;      // 524288 floats (2 MB)
  float* Sp   = r7 + (BLD - SPLANE);             // tail of r7 (disjoint from wbuf2/xb)
  unsigned short* ycomb_b = (unsigned short*)r0; // r0 free after gemm xz (h0b dead)
  unsigned short* wbuf2   = (unsigned short*)r7;
  unsigned short* wb_xp   = wbuf2;               // 16384  (64x256)
  unsigned short* wb_out  = wbuf2 + 16384;       // 65536
  unsigned short* wb_fc1  = wbuf2 + 81920;       // 32768
  unsigned short* wb_fc2  = wbuf2 + 114688;      // 32768
  unsigned short* xb      = wbuf2 + 147456;      // BLD bf16
  float*          m1      = r4;
  unsigned short* m2b     = (unsigned short*)r5;

  // 0. weight conversions (single merged kernel)
  cvt_kernel<<<dim3(1088), 256, 0, stream>>>(
      in_proj_w, xproj_w_f, xproj_w_bw, out_proj_w, fc1_w, fc2_w, wbuf1, wbuf2);

  // 1. RMSNorm x0 -> h0b, x1 -> h1b (both bf16)
  rms_kernel<<<dim3(BL,2), 64, 0, stream>>>(x0, w_norm0, h0b, x1, w_norm1, h1b);

  // 2. xz = h0 @ in_proj.T -> xz_b (bf16, one N=512 dispatch)
  gemm_mfma<3><<<dim3(BL/64, 8), 256, 0, stream>>>(
      h0b, wbuf1, nullptr, nullptr, xz_b, BL, XZS, 256);

  // 3. merged xproj (N=64): xd[t][0..31]=fwd dt/B/C, [32..63]=bwd
  gemm_mfma<0><<<dim3(BL/64, 1), 256, 0, stream>>>(
      h1b, wb_xp, xd, nullptr, nullptr, BL, 64, 256);

  // 4. front: conv+silu+delta + local scan w/ C-apply -> pack(y0,de), S, Hout
  front_kernel<<<dim3(CH, BB, 2), 256, 0, stream>>>(
      xz_b, xd, conv_w_f, conv_b_f, conv_w_bw, conv_b_bw,
      dtproj_w_f, dtproj_b_f, dtproj_w_bw, dtproj_b_bw,
      A_log_f, A_log_bw, D_f, D_bw, xde, Sp, Hout);

  // 5. chunk-carry scan (2-level, in-place Hout->Hin)
  scan_p2<<<dim3(2*BB*DD), 64, 0, stream>>>(Sp, Hout, A_log_f, A_log_bw);

  // 6. fused correction + combine + rmsnorm + gate -> ycomb_b (r0)
  back_kernel<<<dim3(CH, BB), 256, 0, stream>>>(
      xde, xd, A_log_f, A_log_bw, Hin, xz_b, norm_y_w, ycomb_b);

  // 7. x = y @ out_proj.T + residual(x0) -> d_out (fp32) + xb (bf16), N=256
  gemm_mfma<1><<<dim3(BL/64, 4), 256, 0, stream>>>(
      ycomb_b, wb_out, out, x0, xb, BL, 256, 256);

  // 8. m1 = x @ fc1.T (fp32; overwrites dead xde), N=128
  gemm_mfma<0><<<dim3(BL/64, 2), 256, 0, stream>>>(
      xb, wb_fc1, m1, nullptr, nullptr, BL, 128, 256);

  // 9. m2 = silu(dwconv3(m1)) -> bf16
  dwconv3_kernel<<<dim3((BL*HID/4)/256), 256, 0, stream>>>(m1, dw_w, dw_b, m2b);

  // 10. out = x + m2 @ fc2.T, N=256, K=128
  gemm_mfma<2><<<dim3(BL/64, 4), 256, 0, stream>>>(
      m2b, wb_fc2, out, out, nullptr, BL, 256, 128);
}

// Round 6
// 251.780 us; speedup vs baseline: 1.0813x; 1.0366x over previous
//
#include <hip/hip_runtime.h>
#include <math.h>
#include <cstddef>

#define BB 4
#define LL 4096
#define DD 256
#define NST 8
#define RANK 16
#define HID 128
#define BL (BB*LL)          // 16384
#define BLD ((size_t)BL*DD) // 4194304
#define CH 256              // scan chunks
#define CLEN 16             // steps per chunk (CH*CLEN == LL)
#define XZS 512             // xz row stride (xin cols 0..255, z cols 256..511)

typedef __bf16 bf16x8 __attribute__((ext_vector_type(8)));
typedef float  f32x4  __attribute__((ext_vector_type(4)));

__device__ __forceinline__ float siluf(float x){ return x / (1.f + __expf(-x)); }
__device__ __forceinline__ float softplus_fast(float x){
  float r = __logf(1.f + __expf(x));
  return x > 15.f ? x : r;
}
// fp32 -> bf16 bits, round-to-nearest-even
__device__ __forceinline__ unsigned short f2bf(float x){
  union { float f; unsigned u; } v; v.f = x;
  unsigned r = v.u + 0x7fffu + ((v.u >> 16) & 1u);
  return (unsigned short)(r >> 16);
}
__device__ __forceinline__ float bf2f(unsigned short u){
  union { unsigned u32; float f; } c; c.u32 = ((unsigned)u) << 16;
  return c.f;
}

// =============== Pre: RMSNorm (both streams) + weight cvt, ONE dispatch ==========
// blocks [0,4096): x0 rms, 4 tokens/block (1/wave). [4096,8192): x1 rms.
// [8192,9280): fp32->bf16 weight conversion (in_proj -> d1, rest -> d2).
__global__ __launch_bounds__(256) void pre_kernel(
    const float* __restrict__ x0, const float* __restrict__ w0, unsigned short* __restrict__ o0b,
    const float* __restrict__ x1, const float* __restrict__ w1, unsigned short* __restrict__ o1b,
    const float* __restrict__ sA,
    const float* __restrict__ s0, const float* __restrict__ s1,
    const float* __restrict__ s2, const float* __restrict__ s3,
    const float* __restrict__ s4,
    unsigned short* __restrict__ d1, unsigned short* __restrict__ d2)
{
  int blk = blockIdx.x;
  if (blk < 8192){
    const float* x; const float* w; unsigned short* o; size_t tok;
    int wv = threadIdx.x >> 6, lane = threadIdx.x & 63;
    if (blk < 4096){ x = x0; w = w0; o = o0b; tok = (size_t)blk*4 + wv; }
    else           { x = x1; w = w1; o = o1b; tok = (size_t)(blk-4096)*4 + wv; }
    float4 v = ((const float4*)(x + tok*DD))[lane];
    float s = v.x*v.x + v.y*v.y + v.z*v.z + v.w*v.w;
    #pragma unroll
    for (int m = 1; m < 64; m <<= 1) s += __shfl_xor(s, m, 64);
    float scale = 1.f / (sqrtf(s) * (1.f/16.f) + 1e-6f);
    float4 wvv = ((const float4*)w)[lane];
    ushort4 r;
    r.x = f2bf(v.x*scale*wvv.x); r.y = f2bf(v.y*scale*wvv.y);
    r.z = f2bf(v.z*scale*wvv.z); r.w = f2bf(v.w*scale*wvv.w);
    ((ushort4*)(o + tok*DD))[lane] = r;
    return;
  }
  int i = (blk - 8192)*256 + threadIdx.x;   // 0..278527
  if (i >= 278528) return;
  if (i < 131072){ d1[i] = f2bf(sA[i]); return; }
  int j = i - 131072;
  float v;
  if (j < 8192)        v = s0[j];
  else if (j < 16384)  v = s1[j - 8192];
  else if (j < 81920)  v = s2[j - 16384];
  else if (j < 114688) v = s3[j - 81920];
  else                 v = s4[j - 114688];
  d2[j] = f2bf(v);
}

// ---------------- bf16 MFMA GEMM, 64x64 tile, BK=64: C = A @ Bw^T (+ epilogue) ---
// EPI: 0 = C=acc ; 2 = C=acc+Add ; 3 = Cb=bf16(acc)
// Measured-best GEMM structure for these small-K skinny-N shapes (r4: 128-tile
// regressed +27us; r2: BK 32->64 was part of a ~22us gain). Do not touch body.
template<int EPI>
__global__ __launch_bounds__(256) void gemm_mfma(
    const unsigned short* __restrict__ A, const unsigned short* __restrict__ Bw,
    float* __restrict__ C, const float* __restrict__ Add,
    unsigned short* __restrict__ Cb, int M, int ldc, int K)
{
  constexpr int BK = 64, PAD = 8;
  __shared__ __align__(16) unsigned short As[64][BK+PAD];
  __shared__ __align__(16) unsigned short Bs[64][BK+PAD];
  int tid  = threadIdx.x;
  int row0 = blockIdx.x * 64;
  int col0 = blockIdx.y * 64;
  int wave = tid >> 6, lane = tid & 63;
  int wm = (wave >> 1) * 32, wn = (wave & 1) * 32;
  int lm = lane & 15, kq = lane >> 4;
  int sr = tid >> 2, sc16 = (tid & 3) * 16;

  f32x4 acc[2][2];
  #pragma unroll
  for (int i = 0; i < 2; i++)
    #pragma unroll
    for (int j = 0; j < 2; j++) acc[i][j] = (f32x4){0.f,0.f,0.f,0.f};

  for (int k0 = 0; k0 < K; k0 += BK){
    const unsigned short* ap = &A [(size_t)(row0 + sr)*K + k0 + sc16];
    const unsigned short* bp = &Bw[(size_t)(col0 + sr)*K + k0 + sc16];
    *(int4*)&As[sr][sc16]   = *(const int4*)ap;
    *(int4*)&As[sr][sc16+8] = *(const int4*)(ap + 8);
    *(int4*)&Bs[sr][sc16]   = *(const int4*)bp;
    *(int4*)&Bs[sr][sc16+8] = *(const int4*)(bp + 8);
    __syncthreads();
    #pragma unroll
    for (int ks = 0; ks < 2; ks++){
      bf16x8 af[2], bfv[2];
      #pragma unroll
      for (int i = 0; i < 2; i++) af[i]  = *(const bf16x8*)&As[wm + i*16 + lm][ks*32 + kq*8];
      #pragma unroll
      for (int j = 0; j < 2; j++) bfv[j] = *(const bf16x8*)&Bs[wn + j*16 + lm][ks*32 + kq*8];
      #pragma unroll
      for (int i = 0; i < 2; i++)
        #pragma unroll
        for (int j = 0; j < 2; j++)
          acc[i][j] = __builtin_amdgcn_mfma_f32_16x16x32_bf16(af[i], bfv[j], acc[i][j], 0, 0, 0);
    }
    __syncthreads();
  }

  // C/D layout: col = lane&15, row = (lane>>4)*4 + reg   [m89-verified]
  #pragma unroll
  for (int i = 0; i < 2; i++){
    int rbase = row0 + wm + i*16 + kq*4;
    #pragma unroll
    for (int j = 0; j < 2; j++){
      int col = col0 + wn + j*16 + lm;
      #pragma unroll
      for (int r = 0; r < 4; r++){
        size_t idx = (size_t)(rbase + r)*ldc + col;
        float v = acc[i][j][r];
        if constexpr (EPI == 2) v += Add[idx];
        if constexpr (EPI != 3) C[idx] = v;
        if constexpr (EPI == 3) Cb[idx] = f2bf(v);
      }
    }
  }
}

// =============== Merged xz + xproj GEMM: one dispatch, grid (BL/64, 9) ===========
// y<8: xz col-tile y (A=h0b, B=in_proj, bf16 out, ldc XZS).
// y==8: xproj (A=h1b, B=xproj merged, fp32 out, ldc 64).
__global__ __launch_bounds__(256) void gemm_xzxp(
    const unsigned short* __restrict__ A0, const unsigned short* __restrict__ A1,
    const unsigned short* __restrict__ B0, const unsigned short* __restrict__ B1,
    unsigned short* __restrict__ Cxz, float* __restrict__ Cxd)
{
  constexpr int BK = 64, PAD = 8, K = 256;
  __shared__ __align__(16) unsigned short As[64][BK+PAD];
  __shared__ __align__(16) unsigned short Bs[64][BK+PAD];
  int tid  = threadIdx.x;
  bool xp  = (blockIdx.y == 8);
  const unsigned short* A  = xp ? A1 : A0;
  const unsigned short* Bw = xp ? B1 : B0;
  int row0 = blockIdx.x * 64;
  int col0 = xp ? 0 : blockIdx.y * 64;
  int wave = tid >> 6, lane = tid & 63;
  int wm = (wave >> 1) * 32, wn = (wave & 1) * 32;
  int lm = lane & 15, kq = lane >> 4;
  int sr = tid >> 2, sc16 = (tid & 3) * 16;

  f32x4 acc[2][2];
  #pragma unroll
  for (int i = 0; i < 2; i++)
    #pragma unroll
    for (int j = 0; j < 2; j++) acc[i][j] = (f32x4){0.f,0.f,0.f,0.f};

  for (int k0 = 0; k0 < K; k0 += BK){
    const unsigned short* ap = &A [(size_t)(row0 + sr)*K + k0 + sc16];
    const unsigned short* bp = &Bw[(size_t)(col0 + sr)*K + k0 + sc16];
    *(int4*)&As[sr][sc16]   = *(const int4*)ap;
    *(int4*)&As[sr][sc16+8] = *(const int4*)(ap + 8);
    *(int4*)&Bs[sr][sc16]   = *(const int4*)bp;
    *(int4*)&Bs[sr][sc16+8] = *(const int4*)(bp + 8);
    __syncthreads();
    #pragma unroll
    for (int ks = 0; ks < 2; ks++){
      bf16x8 af[2], bfv[2];
      #pragma unroll
      for (int i = 0; i < 2; i++) af[i]  = *(const bf16x8*)&As[wm + i*16 + lm][ks*32 + kq*8];
      #pragma unroll
      for (int j = 0; j < 2; j++) bfv[j] = *(const bf16x8*)&Bs[wn + j*16 + lm][ks*32 + kq*8];
      #pragma unroll
      for (int i = 0; i < 2; i++)
        #pragma unroll
        for (int j = 0; j < 2; j++)
          acc[i][j] = __builtin_amdgcn_mfma_f32_16x16x32_bf16(af[i], bfv[j], acc[i][j], 0, 0, 0);
    }
    __syncthreads();
  }

  #pragma unroll
  for (int i = 0; i < 2; i++){
    int rbase = row0 + wm + i*16 + kq*4;
    #pragma unroll
    for (int j = 0; j < 2; j++){
      int col = col0 + wn + j*16 + lm;
      #pragma unroll
      for (int r = 0; r < 4; r++){
        float v = acc[i][j][r];
        if (xp) Cxd[(size_t)(rbase + r)*64  + col] = v;
        else    Cxz[(size_t)(rbase + r)*XZS + col] = f2bf(v);
      }
    }
  }
}

// =============== fc1: fp32-A GEMM (reads out directly, no xb intermediate) =======
__global__ __launch_bounds__(256) void gemm_fc1(
    const float* __restrict__ A, const unsigned short* __restrict__ Bw,
    float* __restrict__ C)
{
  constexpr int BK = 64, PAD = 8, K = 256, LDC = 128;
  __shared__ __align__(16) unsigned short As[64][BK+PAD];
  __shared__ __align__(16) unsigned short Bs[64][BK+PAD];
  int tid  = threadIdx.x;
  int row0 = blockIdx.x * 64;
  int col0 = blockIdx.y * 64;
  int wave = tid >> 6, lane = tid & 63;
  int wm = (wave >> 1) * 32, wn = (wave & 1) * 32;
  int lm = lane & 15, kq = lane >> 4;
  int sr = tid >> 2, sc16 = (tid & 3) * 16;

  f32x4 acc[2][2];
  #pragma unroll
  for (int i = 0; i < 2; i++)
    #pragma unroll
    for (int j = 0; j < 2; j++) acc[i][j] = (f32x4){0.f,0.f,0.f,0.f};

  for (int k0 = 0; k0 < K; k0 += BK){
    const float* ap = &A[(size_t)(row0 + sr)*K + k0 + sc16];
    #pragma unroll
    for (int q = 0; q < 4; q++){
      float4 f = *(const float4*)(ap + q*4);
      ushort4 u; u.x = f2bf(f.x); u.y = f2bf(f.y); u.z = f2bf(f.z); u.w = f2bf(f.w);
      *(ushort4*)&As[sr][sc16 + q*4] = u;
    }
    const unsigned short* bp = &Bw[(size_t)(col0 + sr)*K + k0 + sc16];
    *(int4*)&Bs[sr][sc16]   = *(const int4*)bp;
    *(int4*)&Bs[sr][sc16+8] = *(const int4*)(bp + 8);
    __syncthreads();
    #pragma unroll
    for (int ks = 0; ks < 2; ks++){
      bf16x8 af[2], bfv[2];
      #pragma unroll
      for (int i = 0; i < 2; i++) af[i]  = *(const bf16x8*)&As[wm + i*16 + lm][ks*32 + kq*8];
      #pragma unroll
      for (int j = 0; j < 2; j++) bfv[j] = *(const bf16x8*)&Bs[wn + j*16 + lm][ks*32 + kq*8];
      #pragma unroll
      for (int i = 0; i < 2; i++)
        #pragma unroll
        for (int j = 0; j < 2; j++)
          acc[i][j] = __builtin_amdgcn_mfma_f32_16x16x32_bf16(af[i], bfv[j], acc[i][j], 0, 0, 0);
    }
    __syncthreads();
  }

  #pragma unroll
  for (int i = 0; i < 2; i++){
    int rbase = row0 + wm + i*16 + kq*4;
    #pragma unroll
    for (int j = 0; j < 2; j++){
      int col = col0 + wn + j*16 + lm;
      #pragma unroll
      for (int r = 0; r < 4; r++)
        C[(size_t)(rbase + r)*LDC + col] = acc[i][j][r];
    }
  }
}

// =============== fc2 with dwconv+silu fused into A-staging =======================
// A[t][c] = silu(dwconv3(m1)[t][c]) computed on the fly from fp32 m1 (halo rows
// read from global; batch-boundary rows zero-padded). out += A @ fc2^T.
__global__ __launch_bounds__(256) void gemm_fc2dw(
    const float* __restrict__ m1, const unsigned short* __restrict__ Bw,
    const float* __restrict__ dww, const float* __restrict__ dwb,
    float* __restrict__ C)
{
  constexpr int BK = 64, PAD = 8, K = 128, LDC = 256;
  __shared__ __align__(16) unsigned short As[64][BK+PAD];
  __shared__ __align__(16) unsigned short Bs[64][BK+PAD];
  __shared__ float wS[HID*3];
  __shared__ float bS[HID];
  int tid  = threadIdx.x;
  if (tid < HID){
    bS[tid] = dwb[tid];
    wS[tid*3+0] = dww[tid*3+0];
    wS[tid*3+1] = dww[tid*3+1];
    wS[tid*3+2] = dww[tid*3+2];
  }
  __syncthreads();

  int row0 = blockIdx.x * 64;
  int col0 = blockIdx.y * 64;
  int wave = tid >> 6, lane = tid & 63;
  int wm = (wave >> 1) * 32, wn = (wave & 1) * 32;
  int lm = lane & 15, kq = lane >> 4;
  int sr = tid >> 2, sc16 = (tid & 3) * 16;
  int r16 = tid >> 4, cc = (tid & 15) * 4;   // A-staging map (coalesced in c)

  f32x4 acc[2][2];
  #pragma unroll
  for (int i = 0; i < 2; i++)
    #pragma unroll
    for (int j = 0; j < 2; j++) acc[i][j] = (f32x4){0.f,0.f,0.f,0.f};

  for (int k0 = 0; k0 < K; k0 += BK){
    // ---- A-stage: dwconv3 + silu from fp32 m1 ----
    #pragma unroll
    for (int pp = 0; pp < 4; pp++){
      int r = pp*16 + r16;
      int t = row0 + r;
      int tl = t & (LL-1);
      int c = k0 + cc;
      const float* mrow = &m1[(size_t)t*HID + c];
      float4 vm = *(const float4*)mrow;
      float4 vp = (tl > 0)      ? *(const float4*)(mrow - HID) : (float4){0,0,0,0};
      float4 vn = (tl < LL-1)   ? *(const float4*)(mrow + HID) : (float4){0,0,0,0};
      float a0 = bS[c+0] + wS[(c+0)*3]*vp.x + wS[(c+0)*3+1]*vm.x + wS[(c+0)*3+2]*vn.x;
      float a1 = bS[c+1] + wS[(c+1)*3]*vp.y + wS[(c+1)*3+1]*vm.y + wS[(c+1)*3+2]*vn.y;
      float a2 = bS[c+2] + wS[(c+2)*3]*vp.z + wS[(c+2)*3+1]*vm.z + wS[(c+2)*3+2]*vn.z;
      float a3 = bS[c+3] + wS[(c+3)*3]*vp.w + wS[(c+3)*3+1]*vm.w + wS[(c+3)*3+2]*vn.w;
      ushort4 u;
      u.x = f2bf(siluf(a0)); u.y = f2bf(siluf(a1));
      u.z = f2bf(siluf(a2)); u.w = f2bf(siluf(a3));
      *(ushort4*)&As[r][cc] = u;
    }
    const unsigned short* bp = &Bw[(size_t)(col0 + sr)*K + k0 + sc16];
    *(int4*)&Bs[sr][sc16]   = *(const int4*)bp;
    *(int4*)&Bs[sr][sc16+8] = *(const int4*)(bp + 8);
    __syncthreads();
    #pragma unroll
    for (int ks = 0; ks < 2; ks++){
      bf16x8 af[2], bfv[2];
      #pragma unroll
      for (int i = 0; i < 2; i++) af[i]  = *(const bf16x8*)&As[wm + i*16 + lm][ks*32 + kq*8];
      #pragma unroll
      for (int j = 0; j < 2; j++) bfv[j] = *(const bf16x8*)&Bs[wn + j*16 + lm][ks*32 + kq*8];
      #pragma unroll
      for (int i = 0; i < 2; i++)
        #pragma unroll
        for (int j = 0; j < 2; j++)
          acc[i][j] = __builtin_amdgcn_mfma_f32_16x16x32_bf16(af[i], bfv[j], acc[i][j], 0, 0, 0);
    }
    __syncthreads();
  }

  #pragma unroll
  for (int i = 0; i < 2; i++){
    int rbase = row0 + wm + i*16 + kq*4;
    #pragma unroll
    for (int j = 0; j < 2; j++){
      int col = col0 + wn + j*16 + lm;
      #pragma unroll
      for (int r = 0; r < 4; r++){
        size_t idx = (size_t)(rbase + r)*LDC + col;
        C[idx] = C[idx] + acc[i][j][r];
      }
    }
  }
}

// =================== Front: conv+silu+delta + local scan w/ C-apply ==============
// MEASURED-BEST STRUCTURE (43.4-43.8us, VGPR 80, occ 24%): split-phase. Known-bad:
// merged loop (67us), e1..e8 power tree (54us, VGPR 88). Do not touch.
__global__ __launch_bounds__(256) void front_kernel(
    const unsigned short* __restrict__ xz,
    const float* __restrict__ xd,
    const float* __restrict__ cwf, const float* __restrict__ cbf,
    const float* __restrict__ cwb, const float* __restrict__ cbb,
    const float* __restrict__ dtwf, const float* __restrict__ dtbf,
    const float* __restrict__ dtwb, const float* __restrict__ dtbb,
    const float* __restrict__ Alogf, const float* __restrict__ Alogb,
    const float* __restrict__ Dfp, const float* __restrict__ Dbp,
    unsigned int* __restrict__ xde,
    float* __restrict__ Sp, float* __restrict__ Hout)
{
  int chunk = blockIdx.x, b = blockIdx.y, dir = blockIdx.z;
  int s0 = chunk*CLEN;
  int d  = threadIdx.x;

  __shared__ float sdt[CLEN][16];   // 1 KB
  __shared__ float sB [CLEN][8];    // 0.5 KB
  __shared__ float sC [CLEN][8];    // 0.5 KB
  #pragma unroll
  for (int e = threadIdx.x; e < CLEN*32; e += 256){
    int lt = e >> 5, col = e & 31;
    int pos = s0 + lt;
    int row = dir ? (LL-1-pos) : pos;
    float v = xd[((size_t)b*LL + row)*64 + dir*32 + col];
    if (col < 16)      sdt[lt][col]    = v;
    else if (col < 24) sB [lt][col-16] = v;
    else               sC [lt][col-24] = v;
  }
  __syncthreads();

  float4 cw = ((const float4*)(dir ? cwb : cwf))[d];
  float cb  = (dir ? cbb : cbf)[d];
  const float* dtw = (dir ? dtwb : dtwf) + d*RANK;
  float4 w0 = ((const float4*)dtw)[0], w1 = ((const float4*)dtw)[1];
  float4 w2 = ((const float4*)dtw)[2], w3 = ((const float4*)dtw)[3];
  float dtb = (dir ? dtbb : dtbf)[d];
  float Dd  = (dir ? Dbp : Dfp)[d];

  const unsigned short* xp = xz + (size_t)b*LL*XZS + d;
  #define LDX(pos) ((pos) >= 0 ? bf2f(xp[(size_t)(dir ? (LL-1-(pos)) : (pos))*XZS]) : 0.f)

  // ---- phase 1: conv + silu + delta, packed into regs (full ILP) ----
  float xv[CLEN+3];
  xv[0] = LDX(s0-3); xv[1] = LDX(s0-2); xv[2] = LDX(s0-1);
  #pragma unroll
  for (int i = 0; i < CLEN; i++) xv[3+i] = LDX(s0+i);
  #undef LDX

  unsigned packX[CLEN];
  #pragma unroll
  for (int i = 0; i < CLEN; i++){
    float xc = cb;
    xc = fmaf(cw.x, xv[i],   xc); xc = fmaf(cw.y, xv[i+1], xc);
    xc = fmaf(cw.z, xv[i+2], xc); xc = fmaf(cw.w, xv[i+3], xc);
    xc = siluf(xc);
    const float* dt = &sdt[i][0];
    float de = dtb;
    de = fmaf(dt[0],w0.x, fmaf(dt[1],w0.y, fmaf(dt[2],w0.z, fmaf(dt[3],w0.w, de))));
    de = fmaf(dt[4],w1.x, fmaf(dt[5],w1.y, fmaf(dt[6],w1.z, fmaf(dt[7],w1.w, de))));
    de = fmaf(dt[8],w2.x, fmaf(dt[9],w2.y, fmaf(dt[10],w2.z, fmaf(dt[11],w2.w, de))));
    de = fmaf(dt[12],w3.x, fmaf(dt[13],w3.y, fmaf(dt[14],w3.z, fmaf(dt[15],w3.w, de))));
    de = softplus_fast(de);
    packX[i] = (unsigned)f2bf(xc) | ((unsigned)f2bf(de) << 16);
  }

  // ---- phase 2: local scan (h from 0) with C-apply; write pack (y0,de) ----
  const float* Alog = dir ? Alogb : Alogf;
  float A[NST];
  bool fast = true;
  #pragma unroll
  for (int n = 0; n < NST; n++){
    A[n] = -__expf(Alog[d*NST + n]);
    fast = fast && (fabsf(A[n] + (float)(n+1)) < 1e-3f);
  }
  float h[NST];
  #pragma unroll
  for (int n = 0; n < NST; n++) h[n] = 0.f;
  float S = 0.f;

  unsigned int* xout = xde + ((size_t)(dir*BB + b)*LL + s0)*DD + d;

  if (fast){
    #pragma unroll
    for (int t = 0; t < CLEN; t++){
      unsigned pk = packX[t];
      float xc = bf2f((unsigned short)(pk & 0xffffu));
      float de = bf2f((unsigned short)(pk >> 16));
      S += de;
      float dux = de * xc;
      const float* Bv = &sB[t][0];
      const float* Cv = &sC[t][0];
      float e1 = __expf(-de);
      float dA = e1;
      float acc = xc * Dd;
      h[0] = fmaf(dA, h[0], dux*Bv[0]); acc = fmaf(h[0], Cv[0], acc); dA *= e1;
      h[1] = fmaf(dA, h[1], dux*Bv[1]); acc = fmaf(h[1], Cv[1], acc); dA *= e1;
      h[2] = fmaf(dA, h[2], dux*Bv[2]); acc = fmaf(h[2], Cv[2], acc); dA *= e1;
      h[3] = fmaf(dA, h[3], dux*Bv[3]); acc = fmaf(h[3], Cv[3], acc); dA *= e1;
      h[4] = fmaf(dA, h[4], dux*Bv[4]); acc = fmaf(h[4], Cv[4], acc); dA *= e1;
      h[5] = fmaf(dA, h[5], dux*Bv[5]); acc = fmaf(h[5], Cv[5], acc); dA *= e1;
      h[6] = fmaf(dA, h[6], dux*Bv[6]); acc = fmaf(h[6], Cv[6], acc); dA *= e1;
      h[7] = fmaf(dA, h[7], dux*Bv[7]); acc = fmaf(h[7], Cv[7], acc);
      xout[(size_t)t*DD] = (pk & 0xffff0000u) | (unsigned)f2bf(acc);
    }
  } else {
    #pragma unroll
    for (int t = 0; t < CLEN; t++){
      unsigned pk = packX[t];
      float xc = bf2f((unsigned short)(pk & 0xffffu));
      float de = bf2f((unsigned short)(pk >> 16));
      S += de;
      float dux = de * xc;
      const float* Bv = &sB[t][0];
      const float* Cv = &sC[t][0];
      float acc = xc * Dd;
      #pragma unroll
      for (int n = 0; n < NST; n++){
        h[n] = fmaf(__expf(de*A[n]), h[n], dux*Bv[n]);
        acc = fmaf(h[n], Cv[n], acc);
      }
      xout[(size_t)t*DD] = (pk & 0xffff0000u) | (unsigned)f2bf(acc);
    }
  }

  size_t ob = ((((size_t)dir*CH + chunk)*BB + b)*DD + d)*NST;
  float4 h0v, h1v;
  h0v.x=h[0]; h0v.y=h[1]; h0v.z=h[2]; h0v.w=h[3];
  h1v.x=h[4]; h1v.y=h[5]; h1v.z=h[6]; h1v.w=h[7];
  *(float4*)&Hout[ob]   = h0v; *(float4*)&Hout[ob+4] = h1v;
  Sp[((size_t)(dir*CH + chunk)*BB + b)*DD + d] = S;
}

// Phase 2: chunk-carry scan, 2-level. Block = (dir,b,d) -> 2048 one-wave blocks.
__global__ __launch_bounds__(64) void scan_p2(
    const float* __restrict__ Sp, float* H,
    const float* __restrict__ Alogf, const float* __restrict__ Alogb)
{
  const int SEGC = CH/8;    // 32 chunks per segment
  int blk = blockIdx.x;
  int d   = blk & (DD-1);
  int b   = (blk >> 8) & (BB-1);
  int dir = blk >> 10;
  int t   = threadIdx.x;
  int seg = t >> 3, n = t & 7;
  float A = -__expf((dir ? Alogb : Alogf)[d*NST + n]);

  const size_t sstr = (size_t)BB*DD;          // per-chunk stride in Sp
  const size_t hstr = (size_t)BB*DD*NST;      // per-chunk stride in H
  size_t sb = (size_t)dir*CH*sstr + (size_t)b*DD + d;
  size_t hb = (size_t)dir*CH*hstr + ((size_t)b*DD + d)*NST + n;
  int c0 = seg*SEGC;

  float pv[SEGC], hv[SEGC];
  #pragma unroll
  for (int k = 0; k < SEGC; k++){
    pv[k] = Sp[sb + (size_t)(c0+k)*sstr];
    hv[k] = H [hb + (size_t)(c0+k)*hstr];
  }
  float h = 0.f, Ss = 0.f;
  #pragma unroll
  for (int k = 0; k < SEGC; k++){
    Ss += pv[k];
    pv[k] = __expf(pv[k]*A);
    h = fmaf(pv[k], h, hv[k]);
  }
  float pi = __expf(Ss*A), hi = h;
  #pragma unroll
  for (int off = 8; off < 64; off <<= 1){
    float hprev = __shfl_up(hi, off, 64);
    float pprev = __shfl_up(pi, off, 64);
    if (t >= off){ hi = fmaf(pi, hprev, hi); pi *= pprev; }
  }
  float hin = __shfl_up(hi, 8, 64);
  h = (seg == 0) ? 0.f : hin;
  #pragma unroll
  for (int k = 0; k < SEGC; k++){
    size_t idx = hb + (size_t)(c0+k)*hstr;
    H[idx] = h;
    h = fmaf(pv[k], h, hv[k]);
  }
}

// =================== Back: correction + combine + rmsnorm + gate ==================
// Serial q*=E chain (measured-best; the E-tree variant regressed via VGPR).
__global__ __launch_bounds__(256) void back_kernel(
    const unsigned int* __restrict__ xde,
    const float* __restrict__ xd,
    const float* __restrict__ Alogf, const float* __restrict__ Alogb,
    const float* __restrict__ Hin,
    const unsigned short* __restrict__ xz,
    const float* __restrict__ wn,
    unsigned short* __restrict__ outb)
{
  int c  = blockIdx.x, b = blockIdx.y;
  int cbk = CH-1-c;
  int d  = threadIdx.x;
  int T0 = c*CLEN;          // token base (fwd storage base)
  int Pb = cbk*CLEN;        // bwd storage base; storage Pb+k <-> token T0+15-k

  __shared__ float sCf[CLEN][8], sCb[CLEN][8];  // 1 KB
  __shared__ float red[CLEN][4];
  __shared__ float sscale[CLEN];
  {
    int k  = threadIdx.x & 7;
    int lt = (threadIdx.x >> 3) & 15;
    if (threadIdx.x < 128)
      sCf[lt][k] = xd[((size_t)b*LL + T0 + lt)*64 + 24 + k];
    else
      sCb[lt][k] = xd[((size_t)b*LL + (T0 + 15 - lt))*64 + 56 + k];
  }
  __syncthreads();

  float Af[NST], Ab[NST];
  bool fast = true;
  #pragma unroll
  for (int n = 0; n < NST; n++){
    Af[n] = -__expf(Alogf[d*NST + n]);
    Ab[n] = -__expf(Alogb[d*NST + n]);
    fast = fast && (fabsf(Af[n] + (float)(n+1)) < 1e-3f)
                && (fabsf(Ab[n] + (float)(n+1)) < 1e-3f);
  }

  float vf[CLEN];

  // ---- forward correction ----
  {
    float hn[NST];
    size_t ib = (((size_t)c*BB + b)*DD + d)*NST;                 // dir=0
    float4 a0 = *(const float4*)&Hin[ib];
    float4 a1 = *(const float4*)&Hin[ib+4];
    hn[0]=a0.x; hn[1]=a0.y; hn[2]=a0.z; hn[3]=a0.w;
    hn[4]=a1.x; hn[5]=a1.y; hn[6]=a1.z; hn[7]=a1.w;
    const unsigned int* p = xde + ((size_t)b*LL + T0)*DD + d;    // dir=0 plane
    unsigned int pk[CLEN];
    #pragma unroll
    for (int t = 0; t < CLEN; t++) pk[t] = p[(size_t)t*DD];
    float S = 0.f;
    if (fast){
      #pragma unroll
      for (int t = 0; t < CLEN; t++){
        float y0 = bf2f((unsigned short)(pk[t] & 0xffffu));
        float de = bf2f((unsigned short)(pk[t] >> 16));
        S += de;
        float E = __expf(-S);
        float q = E;
        float corr = q * (hn[0]*sCf[t][0]);
        q *= E; corr = fmaf(q, hn[1]*sCf[t][1], corr);
        q *= E; corr = fmaf(q, hn[2]*sCf[t][2], corr);
        q *= E; corr = fmaf(q, hn[3]*sCf[t][3], corr);
        q *= E; corr = fmaf(q, hn[4]*sCf[t][4], corr);
        q *= E; corr = fmaf(q, hn[5]*sCf[t][5], corr);
        q *= E; corr = fmaf(q, hn[6]*sCf[t][6], corr);
        q *= E; corr = fmaf(q, hn[7]*sCf[t][7], corr);
        vf[t] = y0 + corr;
      }
    } else {
      #pragma unroll
      for (int t = 0; t < CLEN; t++){
        float y0 = bf2f((unsigned short)(pk[t] & 0xffffu));
        float de = bf2f((unsigned short)(pk[t] >> 16));
        S += de;
        float corr = 0.f;
        #pragma unroll
        for (int n = 0; n < NST; n++)
          corr = fmaf(__expf(S*Af[n]), hn[n]*sCf[t][n], corr);
        vf[t] = y0 + corr;
      }
    }
  }

  // ---- backward correction, merged into vf (token j pairs with bwd k=15-j) ----
  {
    float hn[NST];
    size_t ib = ((((size_t)CH + cbk)*BB + b)*DD + d)*NST;        // dir=1
    float4 a0 = *(const float4*)&Hin[ib];
    float4 a1 = *(const float4*)&Hin[ib+4];
    hn[0]=a0.x; hn[1]=a0.y; hn[2]=a0.z; hn[3]=a0.w;
    hn[4]=a1.x; hn[5]=a1.y; hn[6]=a1.z; hn[7]=a1.w;
    const unsigned int* p = xde + ((size_t)(BB + b)*LL + Pb)*DD + d;  // dir=1 plane
    unsigned int pk[CLEN];
    #pragma unroll
    for (int t = 0; t < CLEN; t++) pk[t] = p[(size_t)t*DD];
    float S = 0.f;
    if (fast){
      #pragma unroll
      for (int t = 0; t < CLEN; t++){
        float y0 = bf2f((unsigned short)(pk[t] & 0xffffu));
        float de = bf2f((unsigned short)(pk[t] >> 16));
        S += de;
        float E = __expf(-S);
        float q = E;
        float corr = q * (hn[0]*sCb[t][0]);
        q *= E; corr = fmaf(q, hn[1]*sCb[t][1], corr);
        q *= E; corr = fmaf(q, hn[2]*sCb[t][2], corr);
        q *= E; corr = fmaf(q, hn[3]*sCb[t][3], corr);
        q *= E; corr = fmaf(q, hn[4]*sCb[t][4], corr);
        q *= E; corr = fmaf(q, hn[5]*sCb[t][5], corr);
        q *= E; corr = fmaf(q, hn[6]*sCb[t][6], corr);
        q *= E; corr = fmaf(q, hn[7]*sCb[t][7], corr);
        int j = 15 - t;
        vf[j] = 0.5f*(vf[j] + y0 + corr);
      }
    } else {
      #pragma unroll
      for (int t = 0; t < CLEN; t++){
        float y0 = bf2f((unsigned short)(pk[t] & 0xffffu));
        float de = bf2f((unsigned short)(pk[t] >> 16));
        S += de;
        float corr = 0.f;
        #pragma unroll
        for (int n = 0; n < NST; n++)
          corr = fmaf(__expf(S*Ab[n]), hn[n]*sCb[t][n], corr);
        int j = 15 - t;
        vf[j] = 0.5f*(vf[j] + y0 + corr);
      }
    }
  }

  // ---- per-token RMS reduce over d ----
  int wave = d >> 6, lane = d & 63;
  #pragma unroll
  for (int j = 0; j < CLEN; j++){
    float s = vf[j]*vf[j];
    #pragma unroll
    for (int m = 1; m < 64; m <<= 1) s += __shfl_xor(s, m, 64);
    if (lane == 0) red[j][wave] = s;
  }
  __syncthreads();
  if (d < CLEN){
    float s = red[d][0] + red[d][1] + red[d][2] + red[d][3];
    sscale[d] = 1.f / (sqrtf(s)*(1.f/16.f) + 1e-6f);
  }
  __syncthreads();

  float wd = wn[d];
  #pragma unroll
  for (int j = 0; j < CLEN; j++){
    size_t tok = (size_t)b*LL + T0 + j;
    float z = bf2f(xz[tok*XZS + 256 + d]);
    outb[tok*DD + d] = f2bf(vf[j]*sscale[j]*wd*siluf(z));
  }
}

extern "C" void kernel_launch(void* const* d_in, const int* in_sizes, int n_in,
                              void* d_out, int out_size, void* d_ws, size_t ws_size,
                              hipStream_t stream)
{
  const float* x0        = (const float*)d_in[0];
  const float* x1        = (const float*)d_in[1];
  const float* w_norm0   = (const float*)d_in[2];
  const float* w_norm1   = (const float*)d_in[3];
  const float* in_proj_w = (const float*)d_in[4];
  const float* conv_w_f  = (const float*)d_in[5];
  const float* conv_b_f  = (const float*)d_in[6];
  const float* xproj_w_f = (const float*)d_in[7];
  const float* dtproj_w_f= (const float*)d_in[8];
  const float* dtproj_b_f= (const float*)d_in[9];
  const float* A_log_f   = (const float*)d_in[10];
  const float* D_f       = (const float*)d_in[11];
  const float* conv_w_bw = (const float*)d_in[12];
  const float* conv_b_bw = (const float*)d_in[13];
  const float* xproj_w_bw= (const float*)d_in[14];
  const float* dtproj_w_bw=(const float*)d_in[15];
  const float* dtproj_b_bw=(const float*)d_in[16];
  const float* A_log_bw  = (const float*)d_in[17];
  const float* D_bw      = (const float*)d_in[18];
  const float* norm_y_w  = (const float*)d_in[19];
  const float* out_proj_w= (const float*)d_in[20];
  const float* fc1_w     = (const float*)d_in[21];
  const float* dw_w      = (const float*)d_in[22];
  const float* dw_b      = (const float*)d_in[23];
  const float* fc2_w     = (const float*)d_in[24];
  float* out = (float*)d_out;
  float* ws  = (float*)d_ws;

  // region map (floats, BLD each), lifetime-reused
  float* r0 = ws + 0*BLD;   // h0b (bf16) -> ycomb_b (bf16)
  float* r1 = ws + 1*BLD;   // h1b (bf16)
  float* r2 = ws + 2*BLD;   // xz_b (bf16, BL x 512 = full region)
  float* r3 = ws + 3*BLD;   // xd (fp32 BLx64) -- live through back_kernel
  float* r4 = ws + 4*BLD;   // xde pack (y0,de) (uint32, spans r4+r5) -> m1 (fp32)
  float* r5 = ws + 5*BLD;
  float* r6 = ws + 6*BLD;   // wbuf1 (bf16 in_proj) -> Hout (= Hin, in-place p2)
  float* r7 = ws + 7*BLD;   // wbuf2 (bf16 weights) + S-plane (tail)

  unsigned short* h0b   = (unsigned short*)r0;
  unsigned short* h1b   = (unsigned short*)r1;
  unsigned short* xz_b  = (unsigned short*)r2;   // BL x XZS
  float*          xd    = r3;                    // BL x 64 fp32
  unsigned int*   xde   = (unsigned int*)r4;     // 2*BLD dwords = r4+r5
  unsigned short* wbuf1 = (unsigned short*)r6;   // 131072 (512x256)
  float* Hout = r6;                              // 2*CH*BB*DD*NST = BLD floats
  float* Hin  = Hout;                            // p2 rewrites in place
  const size_t SPLANE = (size_t)2*CH*BB*DD;      // 524288 floats (2 MB)
  float* Sp   = r7 + (BLD - SPLANE);             // tail of r7 (disjoint from wbuf2)
  unsigned short* ycomb_b = (unsigned short*)r0; // r0 free after xz gemm (h0b dead)
  unsigned short* wbuf2   = (unsigned short*)r7;
  unsigned short* wb_xp   = wbuf2;               // 16384  (64x256)
  unsigned short* wb_out  = wbuf2 + 16384;       // 65536
  unsigned short* wb_fc1  = wbuf2 + 81920;       // 32768
  unsigned short* wb_fc2  = wbuf2 + 114688;      // 32768
  float*          m1      = r4;                  // BLx128 fp32 (xde dead by then)

  // 1. pre: rms(x0)->h0b, rms(x1)->h1b, weight conversions -- ONE dispatch
  pre_kernel<<<dim3(9280), 256, 0, stream>>>(
      x0, w_norm0, h0b, x1, w_norm1, h1b,
      in_proj_w, xproj_w_f, xproj_w_bw, out_proj_w, fc1_w, fc2_w, wbuf1, wbuf2);

  // 2. merged xz (N=512) + xproj (N=64) GEMM -- ONE dispatch
  gemm_xzxp<<<dim3(BL/64, 9), 256, 0, stream>>>(
      h0b, h1b, wbuf1, wb_xp, xz_b, xd);

  // 3. front: conv+silu+delta + local scan w/ C-apply -> pack(y0,de), S, Hout
  front_kernel<<<dim3(CH, BB, 2), 256, 0, stream>>>(
      xz_b, xd, conv_w_f, conv_b_f, conv_w_bw, conv_b_bw,
      dtproj_w_f, dtproj_b_f, dtproj_w_bw, dtproj_b_bw,
      A_log_f, A_log_bw, D_f, D_bw, xde, Sp, Hout);

  // 4. chunk-carry scan (2-level, in-place Hout->Hin)
  scan_p2<<<dim3(2*BB*DD), 64, 0, stream>>>(Sp, Hout, A_log_f, A_log_bw);

  // 5. fused correction + combine + rmsnorm + gate -> ycomb_b (r0)
  back_kernel<<<dim3(CH, BB), 256, 0, stream>>>(
      xde, xd, A_log_f, A_log_bw, Hin, xz_b, norm_y_w, ycomb_b);

  // 6. x = y @ out_proj.T + residual(x0) -> d_out (fp32 only; no xb)
  gemm_mfma<2><<<dim3(BL/64, 4), 256, 0, stream>>>(
      ycomb_b, wb_out, out, x0, nullptr, BL, 256, 256);

  // 7. m1 = x @ fc1.T (A staged from fp32 out; overwrites dead xde)
  gemm_fc1<<<dim3(BL/64, 2), 256, 0, stream>>>(out, wb_fc1, m1);

  // 8. out += silu(dwconv3(m1)) @ fc2.T  (dwconv fused into A-staging)
  gemm_fc2dw<<<dim3(BL/64, 4), 256, 0, stream>>>(m1, wb_fc2, dw_w, dw_b, out);
}

// Round 7
// 248.620 us; speedup vs baseline: 1.0950x; 1.0127x over previous
//
#include <hip/hip_runtime.h>
#include <math.h>
#include <cstddef>

#define BB 4
#define LL 4096
#define DD 256
#define NST 8
#define RANK 16
#define HID 128
#define BL (BB*LL)          // 16384
#define BLD ((size_t)BL*DD) // 4194304
#define CH 256              // scan chunks
#define CLEN 16             // steps per chunk (CH*CLEN == LL)
#define XZS 512             // xz row stride (xin cols 0..255, z cols 256..511)

typedef __bf16 bf16x8 __attribute__((ext_vector_type(8)));
typedef float  f32x4  __attribute__((ext_vector_type(4)));

__device__ __forceinline__ float siluf(float x){ return x / (1.f + __expf(-x)); }
__device__ __forceinline__ float softplus_fast(float x){
  float r = __logf(1.f + __expf(x));
  return x > 15.f ? x : r;
}
// fp32 -> bf16 bits, round-to-nearest-even
__device__ __forceinline__ unsigned short f2bf(float x){
  union { float f; unsigned u; } v; v.f = x;
  unsigned r = v.u + 0x7fffu + ((v.u >> 16) & 1u);
  return (unsigned short)(r >> 16);
}
__device__ __forceinline__ float bf2f(unsigned short u){
  union { unsigned u32; float f; } c; c.u32 = ((unsigned)u) << 16;
  return c.f;
}

// --- async global->LDS, 16B/lane (1KB/wave-instr), linear LDS dest -------------
// Source is PER-LANE (pre-swizzled); LDS dest must be wave-uniform base (HW
// writes base + lane*16). [guide m97/m173/rule#21]
#define GLD16(gp, lp) __builtin_amdgcn_global_load_lds( \
    (const __attribute__((address_space(1))) unsigned int*)(gp), \
    (__attribute__((address_space(3))) unsigned int*)(lp), 16, 0, 0)

// swizzled-granule read: logical (row, g16) -> granule row*8 + (g16 ^ (row&7)).
// 16B granules; reads are <=2 lanes/bank (free, m136).
#define LDSG(base, row, gq) \
  (*(const bf16x8*)((base) + ((((row) << 3) + ((gq) ^ ((row) & 7))) << 3)))

// =============== Pre: RMSNorm (both streams) + weight cvt, ONE dispatch ==========
__global__ __launch_bounds__(256) void pre_kernel(
    const float* __restrict__ x0, const float* __restrict__ w0, unsigned short* __restrict__ o0b,
    const float* __restrict__ x1, const float* __restrict__ w1, unsigned short* __restrict__ o1b,
    const float* __restrict__ sA,
    const float* __restrict__ s0, const float* __restrict__ s1,
    const float* __restrict__ s2, const float* __restrict__ s3,
    const float* __restrict__ s4,
    unsigned short* __restrict__ d1, unsigned short* __restrict__ d2)
{
  int blk = blockIdx.x;
  if (blk < 8192){
    const float* x; const float* w; unsigned short* o; size_t tok;
    int wv = threadIdx.x >> 6, lane = threadIdx.x & 63;
    if (blk < 4096){ x = x0; w = w0; o = o0b; tok = (size_t)blk*4 + wv; }
    else           { x = x1; w = w1; o = o1b; tok = (size_t)(blk-4096)*4 + wv; }
    float4 v = ((const float4*)(x + tok*DD))[lane];
    float s = v.x*v.x + v.y*v.y + v.z*v.z + v.w*v.w;
    #pragma unroll
    for (int m = 1; m < 64; m <<= 1) s += __shfl_xor(s, m, 64);
    float scale = 1.f / (sqrtf(s) * (1.f/16.f) + 1e-6f);
    float4 wvv = ((const float4*)w)[lane];
    ushort4 r;
    r.x = f2bf(v.x*scale*wvv.x); r.y = f2bf(v.y*scale*wvv.y);
    r.z = f2bf(v.z*scale*wvv.z); r.w = f2bf(v.w*scale*wvv.w);
    ((ushort4*)(o + tok*DD))[lane] = r;
    return;
  }
  int i = (blk - 8192)*256 + threadIdx.x;   // 0..278527
  if (i >= 278528) return;
  if (i < 131072){ d1[i] = f2bf(sA[i]); return; }
  int j = i - 131072;
  float v;
  if (j < 8192)        v = s0[j];
  else if (j < 16384)  v = s1[j - 8192];
  else if (j < 81920)  v = s2[j - 16384];
  else if (j < 114688) v = s3[j - 81920];
  else                 v = s4[j - 114688];
  d2[j] = f2bf(v);
}

// ---------------- bf16 MFMA GEMM, 64x64 tile, BK=64, global_load_lds staging -----
// EPI: 0 = C=acc ; 2 = C=acc+Add ; 3 = Cb=bf16(acc)
template<int EPI>
__global__ __launch_bounds__(256) void gemm_mfma(
    const unsigned short* __restrict__ A, const unsigned short* __restrict__ Bw,
    float* __restrict__ C, const float* __restrict__ Add,
    unsigned short* __restrict__ Cb, int M, int ldc, int K)
{
  constexpr int BK = 64;
  __shared__ __align__(16) unsigned short AsL[64*64];
  __shared__ __align__(16) unsigned short BsL[64*64];
  int tid  = threadIdx.x;
  int row0 = blockIdx.x * 64;
  int col0 = blockIdx.y * 64;
  int wave = tid >> 6, lane = tid & 63;
  int wm = (wave >> 1) * 32, wn = (wave & 1) * 32;
  int lm = lane & 15, kq = lane >> 4;

  // per-lane pre-swizzled sources: granule q holds logical (r=q>>3, g=(q&7)^(r&7))
  int q0 = wave*128 + lane, q1 = q0 + 64;
  int ra = q0 >> 3, ga = (q0 & 7) ^ (ra & 7);
  int rb = q1 >> 3, gb = (q1 & 7) ^ (rb & 7);
  const unsigned short* A0 = A  + (size_t)(row0 + ra)*K + ga*8;
  const unsigned short* A1 = A  + (size_t)(row0 + rb)*K + gb*8;
  const unsigned short* B0 = Bw + (size_t)(col0 + ra)*K + ga*8;
  const unsigned short* B1 = Bw + (size_t)(col0 + rb)*K + gb*8;
  unsigned short* lA0 = AsL + wave*1024;   // wave-uniform LDS bases
  unsigned short* lB0 = BsL + wave*1024;

  f32x4 acc[2][2];
  #pragma unroll
  for (int i = 0; i < 2; i++)
    #pragma unroll
    for (int j = 0; j < 2; j++) acc[i][j] = (f32x4){0.f,0.f,0.f,0.f};

  for (int k0 = 0; k0 < K; k0 += BK){
    GLD16(A0 + k0, lA0);       GLD16(A1 + k0, lA0 + 512);
    GLD16(B0 + k0, lB0);       GLD16(B1 + k0, lB0 + 512);
    __syncthreads();
    #pragma unroll
    for (int ks = 0; ks < 2; ks++){
      bf16x8 af[2], bfv[2];
      #pragma unroll
      for (int i = 0; i < 2; i++) af[i]  = LDSG(AsL, wm + i*16 + lm, ks*4 + kq);
      #pragma unroll
      for (int j = 0; j < 2; j++) bfv[j] = LDSG(BsL, wn + j*16 + lm, ks*4 + kq);
      #pragma unroll
      for (int i = 0; i < 2; i++)
        #pragma unroll
        for (int j = 0; j < 2; j++)
          acc[i][j] = __builtin_amdgcn_mfma_f32_16x16x32_bf16(af[i], bfv[j], acc[i][j], 0, 0, 0);
    }
    __syncthreads();
  }

  // C/D layout: col = lane&15, row = (lane>>4)*4 + reg   [m89-verified]
  #pragma unroll
  for (int i = 0; i < 2; i++){
    int rbase = row0 + wm + i*16 + kq*4;
    #pragma unroll
    for (int j = 0; j < 2; j++){
      int col = col0 + wn + j*16 + lm;
      #pragma unroll
      for (int r = 0; r < 4; r++){
        size_t idx = (size_t)(rbase + r)*ldc + col;
        float v = acc[i][j][r];
        if constexpr (EPI == 2) v += Add[idx];
        if constexpr (EPI != 3) C[idx] = v;
        if constexpr (EPI == 3) Cb[idx] = f2bf(v);
      }
    }
  }
}

// =============== Merged xz + xproj GEMM (gload_lds staging) ======================
// y<8: xz col-tile y (A=h0b, B=in_proj, bf16 out). y==8: xproj (A=h1b, fp32 out).
__global__ __launch_bounds__(256) void gemm_xzxp(
    const unsigned short* __restrict__ A0i, const unsigned short* __restrict__ A1i,
    const unsigned short* __restrict__ B0i, const unsigned short* __restrict__ B1i,
    unsigned short* __restrict__ Cxz, float* __restrict__ Cxd)
{
  constexpr int BK = 64, K = 256;
  __shared__ __align__(16) unsigned short AsL[64*64];
  __shared__ __align__(16) unsigned short BsL[64*64];
  int tid  = threadIdx.x;
  bool xp  = (blockIdx.y == 8);
  const unsigned short* A  = xp ? A1i : A0i;
  const unsigned short* Bw = xp ? B1i : B0i;
  int row0 = blockIdx.x * 64;
  int col0 = xp ? 0 : blockIdx.y * 64;
  int wave = tid >> 6, lane = tid & 63;
  int wm = (wave >> 1) * 32, wn = (wave & 1) * 32;
  int lm = lane & 15, kq = lane >> 4;

  int q0 = wave*128 + lane, q1 = q0 + 64;
  int ra = q0 >> 3, ga = (q0 & 7) ^ (ra & 7);
  int rb = q1 >> 3, gb = (q1 & 7) ^ (rb & 7);
  const unsigned short* A0 = A  + (size_t)(row0 + ra)*K + ga*8;
  const unsigned short* A1 = A  + (size_t)(row0 + rb)*K + gb*8;
  const unsigned short* B0 = Bw + (size_t)(col0 + ra)*K + ga*8;
  const unsigned short* B1 = Bw + (size_t)(col0 + rb)*K + gb*8;
  unsigned short* lA0 = AsL + wave*1024;
  unsigned short* lB0 = BsL + wave*1024;

  f32x4 acc[2][2];
  #pragma unroll
  for (int i = 0; i < 2; i++)
    #pragma unroll
    for (int j = 0; j < 2; j++) acc[i][j] = (f32x4){0.f,0.f,0.f,0.f};

  for (int k0 = 0; k0 < K; k0 += BK){
    GLD16(A0 + k0, lA0);       GLD16(A1 + k0, lA0 + 512);
    GLD16(B0 + k0, lB0);       GLD16(B1 + k0, lB0 + 512);
    __syncthreads();
    #pragma unroll
    for (int ks = 0; ks < 2; ks++){
      bf16x8 af[2], bfv[2];
      #pragma unroll
      for (int i = 0; i < 2; i++) af[i]  = LDSG(AsL, wm + i*16 + lm, ks*4 + kq);
      #pragma unroll
      for (int j = 0; j < 2; j++) bfv[j] = LDSG(BsL, wn + j*16 + lm, ks*4 + kq);
      #pragma unroll
      for (int i = 0; i < 2; i++)
        #pragma unroll
        for (int j = 0; j < 2; j++)
          acc[i][j] = __builtin_amdgcn_mfma_f32_16x16x32_bf16(af[i], bfv[j], acc[i][j], 0, 0, 0);
    }
    __syncthreads();
  }

  #pragma unroll
  for (int i = 0; i < 2; i++){
    int rbase = row0 + wm + i*16 + kq*4;
    #pragma unroll
    for (int j = 0; j < 2; j++){
      int col = col0 + wn + j*16 + lm;
      #pragma unroll
      for (int r = 0; r < 4; r++){
        float v = acc[i][j][r];
        if (xp) Cxd[(size_t)(rbase + r)*64  + col] = v;
        else    Cxz[(size_t)(rbase + r)*XZS + col] = f2bf(v);
      }
    }
  }
}

// =============== fc1: fp32-A GEMM (A padded-LDS convert; B gload_lds) ============
__global__ __launch_bounds__(256) void gemm_fc1(
    const float* __restrict__ A, const unsigned short* __restrict__ Bw,
    float* __restrict__ C)
{
  constexpr int BK = 64, PAD = 8, K = 256, LDC = 128;
  __shared__ __align__(16) unsigned short As[64][BK+PAD];
  __shared__ __align__(16) unsigned short BsL[64*64];
  int tid  = threadIdx.x;
  int row0 = blockIdx.x * 64;
  int col0 = blockIdx.y * 64;
  int wave = tid >> 6, lane = tid & 63;
  int wm = (wave >> 1) * 32, wn = (wave & 1) * 32;
  int lm = lane & 15, kq = lane >> 4;
  int sr = tid >> 2, sc16 = (tid & 3) * 16;

  int q0 = wave*128 + lane, q1 = q0 + 64;
  int ra = q0 >> 3, ga = (q0 & 7) ^ (ra & 7);
  int rb = q1 >> 3, gb = (q1 & 7) ^ (rb & 7);
  const unsigned short* B0 = Bw + (size_t)(col0 + ra)*K + ga*8;
  const unsigned short* B1 = Bw + (size_t)(col0 + rb)*K + gb*8;
  unsigned short* lB0 = BsL + wave*1024;

  f32x4 acc[2][2];
  #pragma unroll
  for (int i = 0; i < 2; i++)
    #pragma unroll
    for (int j = 0; j < 2; j++) acc[i][j] = (f32x4){0.f,0.f,0.f,0.f};

  for (int k0 = 0; k0 < K; k0 += BK){
    GLD16(B0 + k0, lB0);       GLD16(B1 + k0, lB0 + 512);
    const float* ap = &A[(size_t)(row0 + sr)*K + k0 + sc16];
    #pragma unroll
    for (int q = 0; q < 4; q++){
      float4 f = *(const float4*)(ap + q*4);
      ushort4 u; u.x = f2bf(f.x); u.y = f2bf(f.y); u.z = f2bf(f.z); u.w = f2bf(f.w);
      *(ushort4*)&As[sr][sc16 + q*4] = u;
    }
    __syncthreads();
    #pragma unroll
    for (int ks = 0; ks < 2; ks++){
      bf16x8 af[2], bfv[2];
      #pragma unroll
      for (int i = 0; i < 2; i++) af[i]  = *(const bf16x8*)&As[wm + i*16 + lm][ks*32 + kq*8];
      #pragma unroll
      for (int j = 0; j < 2; j++) bfv[j] = LDSG(BsL, wn + j*16 + lm, ks*4 + kq);
      #pragma unroll
      for (int i = 0; i < 2; i++)
        #pragma unroll
        for (int j = 0; j < 2; j++)
          acc[i][j] = __builtin_amdgcn_mfma_f32_16x16x32_bf16(af[i], bfv[j], acc[i][j], 0, 0, 0);
    }
    __syncthreads();
  }

  #pragma unroll
  for (int i = 0; i < 2; i++){
    int rbase = row0 + wm + i*16 + kq*4;
    #pragma unroll
    for (int j = 0; j < 2; j++){
      int col = col0 + wn + j*16 + lm;
      #pragma unroll
      for (int r = 0; r < 4; r++)
        C[(size_t)(rbase + r)*LDC + col] = acc[i][j][r];
    }
  }
}

// =============== fc2 with dwconv+silu fused into A-staging (B gload_lds) =========
__global__ __launch_bounds__(256) void gemm_fc2dw(
    const float* __restrict__ m1, const unsigned short* __restrict__ Bw,
    const float* __restrict__ dww, const float* __restrict__ dwb,
    float* __restrict__ C)
{
  constexpr int BK = 64, PAD = 8, K = 128, LDC = 256;
  __shared__ __align__(16) unsigned short As[64][BK+PAD];
  __shared__ __align__(16) unsigned short BsL[64*64];
  __shared__ float wS[HID*3];
  __shared__ float bS[HID];
  int tid  = threadIdx.x;
  if (tid < HID){
    bS[tid] = dwb[tid];
    wS[tid*3+0] = dww[tid*3+0];
    wS[tid*3+1] = dww[tid*3+1];
    wS[tid*3+2] = dww[tid*3+2];
  }
  __syncthreads();

  int row0 = blockIdx.x * 64;
  int col0 = blockIdx.y * 64;
  int wave = tid >> 6, lane = tid & 63;
  int wm = (wave >> 1) * 32, wn = (wave & 1) * 32;
  int lm = lane & 15, kq = lane >> 4;
  int r16 = tid >> 4, cc = (tid & 15) * 4;   // A-staging map (coalesced in c)

  int q0 = wave*128 + lane, q1 = q0 + 64;
  int ra = q0 >> 3, ga = (q0 & 7) ^ (ra & 7);
  int rb = q1 >> 3, gb = (q1 & 7) ^ (rb & 7);
  const unsigned short* B0 = Bw + (size_t)(col0 + ra)*K + ga*8;
  const unsigned short* B1 = Bw + (size_t)(col0 + rb)*K + gb*8;
  unsigned short* lB0 = BsL + wave*1024;

  f32x4 acc[2][2];
  #pragma unroll
  for (int i = 0; i < 2; i++)
    #pragma unroll
    for (int j = 0; j < 2; j++) acc[i][j] = (f32x4){0.f,0.f,0.f,0.f};

  for (int k0 = 0; k0 < K; k0 += BK){
    GLD16(B0 + k0, lB0);       GLD16(B1 + k0, lB0 + 512);
    // ---- A-stage: dwconv3 + silu from fp32 m1 ----
    #pragma unroll
    for (int pp = 0; pp < 4; pp++){
      int r = pp*16 + r16;
      int t = row0 + r;
      int tl = t & (LL-1);
      int c = k0 + cc;
      const float* mrow = &m1[(size_t)t*HID + c];
      float4 vm = *(const float4*)mrow;
      float4 vp = (tl > 0)      ? *(const float4*)(mrow - HID) : (float4){0,0,0,0};
      float4 vn = (tl < LL-1)   ? *(const float4*)(mrow + HID) : (float4){0,0,0,0};
      float a0 = bS[c+0] + wS[(c+0)*3]*vp.x + wS[(c+0)*3+1]*vm.x + wS[(c+0)*3+2]*vn.x;
      float a1 = bS[c+1] + wS[(c+1)*3]*vp.y + wS[(c+1)*3+1]*vm.y + wS[(c+1)*3+2]*vn.y;
      float a2 = bS[c+2] + wS[(c+2)*3]*vp.z + wS[(c+2)*3+1]*vm.z + wS[(c+2)*3+2]*vn.z;
      float a3 = bS[c+3] + wS[(c+3)*3]*vp.w + wS[(c+3)*3+1]*vm.w + wS[(c+3)*3+2]*vn.w;
      ushort4 u;
      u.x = f2bf(siluf(a0)); u.y = f2bf(siluf(a1));
      u.z = f2bf(siluf(a2)); u.w = f2bf(siluf(a3));
      *(ushort4*)&As[r][cc] = u;
    }
    __syncthreads();
    #pragma unroll
    for (int ks = 0; ks < 2; ks++){
      bf16x8 af[2], bfv[2];
      #pragma unroll
      for (int i = 0; i < 2; i++) af[i]  = *(const bf16x8*)&As[wm + i*16 + lm][ks*32 + kq*8];
      #pragma unroll
      for (int j = 0; j < 2; j++) bfv[j] = LDSG(BsL, wn + j*16 + lm, ks*4 + kq);
      #pragma unroll
      for (int i = 0; i < 2; i++)
        #pragma unroll
        for (int j = 0; j < 2; j++)
          acc[i][j] = __builtin_amdgcn_mfma_f32_16x16x32_bf16(af[i], bfv[j], acc[i][j], 0, 0, 0);
    }
    __syncthreads();
  }

  #pragma unroll
  for (int i = 0; i < 2; i++){
    int rbase = row0 + wm + i*16 + kq*4;
    #pragma unroll
    for (int j = 0; j < 2; j++){
      int col = col0 + wn + j*16 + lm;
      #pragma unroll
      for (int r = 0; r < 4; r++){
        size_t idx = (size_t)(rbase + r)*LDC + col;
        C[idx] = C[idx] + acc[i][j][r];
      }
    }
  }
}

// =================== Front: conv+silu+delta + local scan w/ C-apply ==============
// MEASURED-BEST STRUCTURE (43.4-44.3us, VGPR 80, occ 24%): split-phase. Known-bad:
// merged loop (67us), e1..e8 power tree (54us, VGPR 88). Do not touch.
__global__ __launch_bounds__(256) void front_kernel(
    const unsigned short* __restrict__ xz,
    const float* __restrict__ xd,
    const float* __restrict__ cwf, const float* __restrict__ cbf,
    const float* __restrict__ cwb, const float* __restrict__ cbb,
    const float* __restrict__ dtwf, const float* __restrict__ dtbf,
    const float* __restrict__ dtwb, const float* __restrict__ dtbb,
    const float* __restrict__ Alogf, const float* __restrict__ Alogb,
    const float* __restrict__ Dfp, const float* __restrict__ Dbp,
    unsigned int* __restrict__ xde,
    float* __restrict__ Sp, float* __restrict__ Hout)
{
  int chunk = blockIdx.x, b = blockIdx.y, dir = blockIdx.z;
  int s0 = chunk*CLEN;
  int d  = threadIdx.x;

  __shared__ float sdt[CLEN][16];   // 1 KB
  __shared__ float sB [CLEN][8];    // 0.5 KB
  __shared__ float sC [CLEN][8];    // 0.5 KB
  #pragma unroll
  for (int e = threadIdx.x; e < CLEN*32; e += 256){
    int lt = e >> 5, col = e & 31;
    int pos = s0 + lt;
    int row = dir ? (LL-1-pos) : pos;
    float v = xd[((size_t)b*LL + row)*64 + dir*32 + col];
    if (col < 16)      sdt[lt][col]    = v;
    else if (col < 24) sB [lt][col-16] = v;
    else               sC [lt][col-24] = v;
  }
  __syncthreads();

  float4 cw = ((const float4*)(dir ? cwb : cwf))[d];
  float cb  = (dir ? cbb : cbf)[d];
  const float* dtw = (dir ? dtwb : dtwf) + d*RANK;
  float4 w0 = ((const float4*)dtw)[0], w1 = ((const float4*)dtw)[1];
  float4 w2 = ((const float4*)dtw)[2], w3 = ((const float4*)dtw)[3];
  float dtb = (dir ? dtbb : dtbf)[d];
  float Dd  = (dir ? Dbp : Dfp)[d];

  const unsigned short* xp = xz + (size_t)b*LL*XZS + d;
  #define LDX(pos) ((pos) >= 0 ? bf2f(xp[(size_t)(dir ? (LL-1-(pos)) : (pos))*XZS]) : 0.f)

  // ---- phase 1: conv + silu + delta, packed into regs (full ILP) ----
  float xv[CLEN+3];
  xv[0] = LDX(s0-3); xv[1] = LDX(s0-2); xv[2] = LDX(s0-1);
  #pragma unroll
  for (int i = 0; i < CLEN; i++) xv[3+i] = LDX(s0+i);
  #undef LDX

  unsigned packX[CLEN];
  #pragma unroll
  for (int i = 0; i < CLEN; i++){
    float xc = cb;
    xc = fmaf(cw.x, xv[i],   xc); xc = fmaf(cw.y, xv[i+1], xc);
    xc = fmaf(cw.z, xv[i+2], xc); xc = fmaf(cw.w, xv[i+3], xc);
    xc = siluf(xc);
    const float* dt = &sdt[i][0];
    float de = dtb;
    de = fmaf(dt[0],w0.x, fmaf(dt[1],w0.y, fmaf(dt[2],w0.z, fmaf(dt[3],w0.w, de))));
    de = fmaf(dt[4],w1.x, fmaf(dt[5],w1.y, fmaf(dt[6],w1.z, fmaf(dt[7],w1.w, de))));
    de = fmaf(dt[8],w2.x, fmaf(dt[9],w2.y, fmaf(dt[10],w2.z, fmaf(dt[11],w2.w, de))));
    de = fmaf(dt[12],w3.x, fmaf(dt[13],w3.y, fmaf(dt[14],w3.z, fmaf(dt[15],w3.w, de))));
    de = softplus_fast(de);
    packX[i] = (unsigned)f2bf(xc) | ((unsigned)f2bf(de) << 16);
  }

  // ---- phase 2: local scan (h from 0) with C-apply; write pack (y0,de) ----
  const float* Alog = dir ? Alogb : Alogf;
  float A[NST];
  bool fast = true;
  #pragma unroll
  for (int n = 0; n < NST; n++){
    A[n] = -__expf(Alog[d*NST + n]);
    fast = fast && (fabsf(A[n] + (float)(n+1)) < 1e-3f);
  }
  float h[NST];
  #pragma unroll
  for (int n = 0; n < NST; n++) h[n] = 0.f;
  float S = 0.f;

  unsigned int* xout = xde + ((size_t)(dir*BB + b)*LL + s0)*DD + d;

  if (fast){
    #pragma unroll
    for (int t = 0; t < CLEN; t++){
      unsigned pk = packX[t];
      float xc = bf2f((unsigned short)(pk & 0xffffu));
      float de = bf2f((unsigned short)(pk >> 16));
      S += de;
      float dux = de * xc;
      const float* Bv = &sB[t][0];
      const float* Cv = &sC[t][0];
      float e1 = __expf(-de);
      float dA = e1;
      float acc = xc * Dd;
      h[0] = fmaf(dA, h[0], dux*Bv[0]); acc = fmaf(h[0], Cv[0], acc); dA *= e1;
      h[1] = fmaf(dA, h[1], dux*Bv[1]); acc = fmaf(h[1], Cv[1], acc); dA *= e1;
      h[2] = fmaf(dA, h[2], dux*Bv[2]); acc = fmaf(h[2], Cv[2], acc); dA *= e1;
      h[3] = fmaf(dA, h[3], dux*Bv[3]); acc = fmaf(h[3], Cv[3], acc); dA *= e1;
      h[4] = fmaf(dA, h[4], dux*Bv[4]); acc = fmaf(h[4], Cv[4], acc); dA *= e1;
      h[5] = fmaf(dA, h[5], dux*Bv[5]); acc = fmaf(h[5], Cv[5], acc); dA *= e1;
      h[6] = fmaf(dA, h[6], dux*Bv[6]); acc = fmaf(h[6], Cv[6], acc); dA *= e1;
      h[7] = fmaf(dA, h[7], dux*Bv[7]); acc = fmaf(h[7], Cv[7], acc);
      xout[(size_t)t*DD] = (pk & 0xffff0000u) | (unsigned)f2bf(acc);
    }
  } else {
    #pragma unroll
    for (int t = 0; t < CLEN; t++){
      unsigned pk = packX[t];
      float xc = bf2f((unsigned short)(pk & 0xffffu));
      float de = bf2f((unsigned short)(pk >> 16));
      S += de;
      float dux = de * xc;
      const float* Bv = &sB[t][0];
      const float* Cv = &sC[t][0];
      float acc = xc * Dd;
      #pragma unroll
      for (int n = 0; n < NST; n++){
        h[n] = fmaf(__expf(de*A[n]), h[n], dux*Bv[n]);
        acc = fmaf(h[n], Cv[n], acc);
      }
      xout[(size_t)t*DD] = (pk & 0xffff0000u) | (unsigned)f2bf(acc);
    }
  }

  size_t ob = ((((size_t)dir*CH + chunk)*BB + b)*DD + d)*NST;
  float4 h0v, h1v;
  h0v.x=h[0]; h0v.y=h[1]; h0v.z=h[2]; h0v.w=h[3];
  h1v.x=h[4]; h1v.y=h[5]; h1v.z=h[6]; h1v.w=h[7];
  *(float4*)&Hout[ob]   = h0v; *(float4*)&Hout[ob+4] = h1v;
  Sp[((size_t)(dir*CH + chunk)*BB + b)*DD + d] = S;
}

// Phase 2: chunk-carry scan, 2-level. Block = (dir,b,d) -> 2048 one-wave blocks.
__global__ __launch_bounds__(64) void scan_p2(
    const float* __restrict__ Sp, float* H,
    const float* __restrict__ Alogf, const float* __restrict__ Alogb)
{
  const int SEGC = CH/8;    // 32 chunks per segment
  int blk = blockIdx.x;
  int d   = blk & (DD-1);
  int b   = (blk >> 8) & (BB-1);
  int dir = blk >> 10;
  int t   = threadIdx.x;
  int seg = t >> 3, n = t & 7;
  float A = -__expf((dir ? Alogb : Alogf)[d*NST + n]);

  const size_t sstr = (size_t)BB*DD;          // per-chunk stride in Sp
  const size_t hstr = (size_t)BB*DD*NST;      // per-chunk stride in H
  size_t sb = (size_t)dir*CH*sstr + (size_t)b*DD + d;
  size_t hb = (size_t)dir*CH*hstr + ((size_t)b*DD + d)*NST + n;
  int c0 = seg*SEGC;

  float pv[SEGC], hv[SEGC];
  #pragma unroll
  for (int k = 0; k < SEGC; k++){
    pv[k] = Sp[sb + (size_t)(c0+k)*sstr];
    hv[k] = H [hb + (size_t)(c0+k)*hstr];
  }
  float h = 0.f, Ss = 0.f;
  #pragma unroll
  for (int k = 0; k < SEGC; k++){
    Ss += pv[k];
    pv[k] = __expf(pv[k]*A);
    h = fmaf(pv[k], h, hv[k]);
  }
  float pi = __expf(Ss*A), hi = h;
  #pragma unroll
  for (int off = 8; off < 64; off <<= 1){
    float hprev = __shfl_up(hi, off, 64);
    float pprev = __shfl_up(pi, off, 64);
    if (t >= off){ hi = fmaf(pi, hprev, hi); pi *= pprev; }
  }
  float hin = __shfl_up(hi, 8, 64);
  h = (seg == 0) ? 0.f : hin;
  #pragma unroll
  for (int k = 0; k < SEGC; k++){
    size_t idx = hb + (size_t)(c0+k)*hstr;
    H[idx] = h;
    h = fmaf(pv[k], h, hv[k]);
  }
}

// =================== Back: correction + combine + rmsnorm + gate ==================
// Serial q*=E chain (measured-best; the E-tree variant regressed via VGPR).
__global__ __launch_bounds__(256) void back_kernel(
    const unsigned int* __restrict__ xde,
    const float* __restrict__ xd,
    const float* __restrict__ Alogf, const float* __restrict__ Alogb,
    const float* __restrict__ Hin,
    const unsigned short* __restrict__ xz,
    const float* __restrict__ wn,
    unsigned short* __restrict__ outb)
{
  int c  = blockIdx.x, b = blockIdx.y;
  int cbk = CH-1-c;
  int d  = threadIdx.x;
  int T0 = c*CLEN;          // token base (fwd storage base)
  int Pb = cbk*CLEN;        // bwd storage base; storage Pb+k <-> token T0+15-k

  __shared__ float sCf[CLEN][8], sCb[CLEN][8];  // 1 KB
  __shared__ float red[CLEN][4];
  __shared__ float sscale[CLEN];
  {
    int k  = threadIdx.x & 7;
    int lt = (threadIdx.x >> 3) & 15;
    if (threadIdx.x < 128)
      sCf[lt][k] = xd[((size_t)b*LL + T0 + lt)*64 + 24 + k];
    else
      sCb[lt][k] = xd[((size_t)b*LL + (T0 + 15 - lt))*64 + 56 + k];
  }
  __syncthreads();

  float Af[NST], Ab[NST];
  bool fast = true;
  #pragma unroll
  for (int n = 0; n < NST; n++){
    Af[n] = -__expf(Alogf[d*NST + n]);
    Ab[n] = -__expf(Alogb[d*NST + n]);
    fast = fast && (fabsf(Af[n] + (float)(n+1)) < 1e-3f)
                && (fabsf(Ab[n] + (float)(n+1)) < 1e-3f);
  }

  float vf[CLEN];

  // ---- forward correction ----
  {
    float hn[NST];
    size_t ib = (((size_t)c*BB + b)*DD + d)*NST;                 // dir=0
    float4 a0 = *(const float4*)&Hin[ib];
    float4 a1 = *(const float4*)&Hin[ib+4];
    hn[0]=a0.x; hn[1]=a0.y; hn[2]=a0.z; hn[3]=a0.w;
    hn[4]=a1.x; hn[5]=a1.y; hn[6]=a1.z; hn[7]=a1.w;
    const unsigned int* p = xde + ((size_t)b*LL + T0)*DD + d;    // dir=0 plane
    unsigned int pk[CLEN];
    #pragma unroll
    for (int t = 0; t < CLEN; t++) pk[t] = p[(size_t)t*DD];
    float S = 0.f;
    if (fast){
      #pragma unroll
      for (int t = 0; t < CLEN; t++){
        float y0 = bf2f((unsigned short)(pk[t] & 0xffffu));
        float de = bf2f((unsigned short)(pk[t] >> 16));
        S += de;
        float E = __expf(-S);
        float q = E;
        float corr = q * (hn[0]*sCf[t][0]);
        q *= E; corr = fmaf(q, hn[1]*sCf[t][1], corr);
        q *= E; corr = fmaf(q, hn[2]*sCf[t][2], corr);
        q *= E; corr = fmaf(q, hn[3]*sCf[t][3], corr);
        q *= E; corr = fmaf(q, hn[4]*sCf[t][4], corr);
        q *= E; corr = fmaf(q, hn[5]*sCf[t][5], corr);
        q *= E; corr = fmaf(q, hn[6]*sCf[t][6], corr);
        q *= E; corr = fmaf(q, hn[7]*sCf[t][7], corr);
        vf[t] = y0 + corr;
      }
    } else {
      #pragma unroll
      for (int t = 0; t < CLEN; t++){
        float y0 = bf2f((unsigned short)(pk[t] & 0xffffu));
        float de = bf2f((unsigned short)(pk[t] >> 16));
        S += de;
        float corr = 0.f;
        #pragma unroll
        for (int n = 0; n < NST; n++)
          corr = fmaf(__expf(S*Af[n]), hn[n]*sCf[t][n], corr);
        vf[t] = y0 + corr;
      }
    }
  }

  // ---- backward correction, merged into vf (token j pairs with bwd k=15-j) ----
  {
    float hn[NST];
    size_t ib = ((((size_t)CH + cbk)*BB + b)*DD + d)*NST;        // dir=1
    float4 a0 = *(const float4*)&Hin[ib];
    float4 a1 = *(const float4*)&Hin[ib+4];
    hn[0]=a0.x; hn[1]=a0.y; hn[2]=a0.z; hn[3]=a0.w;
    hn[4]=a1.x; hn[5]=a1.y; hn[6]=a1.z; hn[7]=a1.w;
    const unsigned int* p = xde + ((size_t)(BB + b)*LL + Pb)*DD + d;  // dir=1 plane
    unsigned int pk[CLEN];
    #pragma unroll
    for (int t = 0; t < CLEN; t++) pk[t] = p[(size_t)t*DD];
    float S = 0.f;
    if (fast){
      #pragma unroll
      for (int t = 0; t < CLEN; t++){
        float y0 = bf2f((unsigned short)(pk[t] & 0xffffu));
        float de = bf2f((unsigned short)(pk[t] >> 16));
        S += de;
        float E = __expf(-S);
        float q = E;
        float corr = q * (hn[0]*sCb[t][0]);
        q *= E; corr = fmaf(q, hn[1]*sCb[t][1], corr);
        q *= E; corr = fmaf(q, hn[2]*sCb[t][2], corr);
        q *= E; corr = fmaf(q, hn[3]*sCb[t][3], corr);
        q *= E; corr = fmaf(q, hn[4]*sCb[t][4], corr);
        q *= E; corr = fmaf(q, hn[5]*sCb[t][5], corr);
        q *= E; corr = fmaf(q, hn[6]*sCb[t][6], corr);
        q *= E; corr = fmaf(q, hn[7]*sCb[t][7], corr);
        int j = 15 - t;
        vf[j] = 0.5f*(vf[j] + y0 + corr);
      }
    } else {
      #pragma unroll
      for (int t = 0; t < CLEN; t++){
        float y0 = bf2f((unsigned short)(pk[t] & 0xffffu));
        float de = bf2f((unsigned short)(pk[t] >> 16));
        S += de;
        float corr = 0.f;
        #pragma unroll
        for (int n = 0; n < NST; n++)
          corr = fmaf(__expf(S*Ab[n]), hn[n]*sCb[t][n], corr);
        int j = 15 - t;
        vf[j] = 0.5f*(vf[j] + y0 + corr);
      }
    }
  }

  // ---- per-token RMS reduce over d ----
  int wave = d >> 6, lane = d & 63;
  #pragma unroll
  for (int j = 0; j < CLEN; j++){
    float s = vf[j]*vf[j];
    #pragma unroll
    for (int m = 1; m < 64; m <<= 1) s += __shfl_xor(s, m, 64);
    if (lane == 0) red[j][wave] = s;
  }
  __syncthreads();
  if (d < CLEN){
    float s = red[d][0] + red[d][1] + red[d][2] + red[d][3];
    sscale[d] = 1.f / (sqrtf(s)*(1.f/16.f) + 1e-6f);
  }
  __syncthreads();

  float wd = wn[d];
  #pragma unroll
  for (int j = 0; j < CLEN; j++){
    size_t tok = (size_t)b*LL + T0 + j;
    float z = bf2f(xz[tok*XZS + 256 + d]);
    outb[tok*DD + d] = f2bf(vf[j]*sscale[j]*wd*siluf(z));
  }
}

extern "C" void kernel_launch(void* const* d_in, const int* in_sizes, int n_in,
                              void* d_out, int out_size, void* d_ws, size_t ws_size,
                              hipStream_t stream)
{
  const float* x0        = (const float*)d_in[0];
  const float* x1        = (const float*)d_in[1];
  const float* w_norm0   = (const float*)d_in[2];
  const float* w_norm1   = (const float*)d_in[3];
  const float* in_proj_w = (const float*)d_in[4];
  const float* conv_w_f  = (const float*)d_in[5];
  const float* conv_b_f  = (const float*)d_in[6];
  const float* xproj_w_f = (const float*)d_in[7];
  const float* dtproj_w_f= (const float*)d_in[8];
  const float* dtproj_b_f= (const float*)d_in[9];
  const float* A_log_f   = (const float*)d_in[10];
  const float* D_f       = (const float*)d_in[11];
  const float* conv_w_bw = (const float*)d_in[12];
  const float* conv_b_bw = (const float*)d_in[13];
  const float* xproj_w_bw= (const float*)d_in[14];
  const float* dtproj_w_bw=(const float*)d_in[15];
  const float* dtproj_b_bw=(const float*)d_in[16];
  const float* A_log_bw  = (const float*)d_in[17];
  const float* D_bw      = (const float*)d_in[18];
  const float* norm_y_w  = (const float*)d_in[19];
  const float* out_proj_w= (const float*)d_in[20];
  const float* fc1_w     = (const float*)d_in[21];
  const float* dw_w      = (const float*)d_in[22];
  const float* dw_b      = (const float*)d_in[23];
  const float* fc2_w     = (const float*)d_in[24];
  float* out = (float*)d_out;
  float* ws  = (float*)d_ws;

  // region map (floats, BLD each), lifetime-reused
  float* r0 = ws + 0*BLD;   // h0b (bf16) -> ycomb_b (bf16)
  float* r1 = ws + 1*BLD;   // h1b (bf16)
  float* r2 = ws + 2*BLD;   // xz_b (bf16, BL x 512 = full region)
  float* r3 = ws + 3*BLD;   // xd (fp32 BLx64) -- live through back_kernel
  float* r4 = ws + 4*BLD;   // xde pack (y0,de) (uint32, spans r4+r5) -> m1 (fp32)
  float* r5 = ws + 5*BLD;
  float* r6 = ws + 6*BLD;   // wbuf1 (bf16 in_proj) -> Hout (= Hin, in-place p2)
  float* r7 = ws + 7*BLD;   // wbuf2 (bf16 weights) + S-plane (tail)

  unsigned short* h0b   = (unsigned short*)r0;
  unsigned short* h1b   = (unsigned short*)r1;
  unsigned short* xz_b  = (unsigned short*)r2;   // BL x XZS
  float*          xd    = r3;                    // BL x 64 fp32
  unsigned int*   xde   = (unsigned int*)r4;     // 2*BLD dwords = r4+r5
  unsigned short* wbuf1 = (unsigned short*)r6;   // 131072 (512x256)
  float* Hout = r6;                              // 2*CH*BB*DD*NST = BLD floats
  float* Hin  = Hout;                            // p2 rewrites in place
  const size_t SPLANE = (size_t)2*CH*BB*DD;      // 524288 floats (2 MB)
  float* Sp   = r7 + (BLD - SPLANE);             // tail of r7 (disjoint from wbuf2)
  unsigned short* ycomb_b = (unsigned short*)r0; // r0 free after xz gemm (h0b dead)
  unsigned short* wbuf2   = (unsigned short*)r7;
  unsigned short* wb_xp   = wbuf2;               // 16384  (64x256)
  unsigned short* wb_out  = wbuf2 + 16384;       // 65536
  unsigned short* wb_fc1  = wbuf2 + 81920;       // 32768
  unsigned short* wb_fc2  = wbuf2 + 114688;      // 32768
  float*          m1      = r4;                  // BLx128 fp32 (xde dead by then)

  // 1. pre: rms(x0)->h0b, rms(x1)->h1b, weight conversions -- ONE dispatch
  pre_kernel<<<dim3(9280), 256, 0, stream>>>(
      x0, w_norm0, h0b, x1, w_norm1, h1b,
      in_proj_w, xproj_w_f, xproj_w_bw, out_proj_w, fc1_w, fc2_w, wbuf1, wbuf2);

  // 2. merged xz (N=512) + xproj (N=64) GEMM -- ONE dispatch
  gemm_xzxp<<<dim3(BL/64, 9), 256, 0, stream>>>(
      h0b, h1b, wbuf1, wb_xp, xz_b, xd);

  // 3. front: conv+silu+delta + local scan w/ C-apply -> pack(y0,de), S, Hout
  front_kernel<<<dim3(CH, BB, 2), 256, 0, stream>>>(
      xz_b, xd, conv_w_f, conv_b_f, conv_w_bw, conv_b_bw,
      dtproj_w_f, dtproj_b_f, dtproj_w_bw, dtproj_b_bw,
      A_log_f, A_log_bw, D_f, D_bw, xde, Sp, Hout);

  // 4. chunk-carry scan (2-level, in-place Hout->Hin)
  scan_p2<<<dim3(2*BB*DD), 64, 0, stream>>>(Sp, Hout, A_log_f, A_log_bw);

  // 5. fused correction + combine + rmsnorm + gate -> ycomb_b (r0)
  back_kernel<<<dim3(CH, BB), 256, 0, stream>>>(
      xde, xd, A_log_f, A_log_bw, Hin, xz_b, norm_y_w, ycomb_b);

  // 6. x = y @ out_proj.T + residual(x0) -> d_out (fp32 only)
  gemm_mfma<2><<<dim3(BL/64, 4), 256, 0, stream>>>(
      ycomb_b, wb_out, out, x0, nullptr, BL, 256, 256);

  // 7. m1 = x @ fc1.T (A staged from fp32 out; overwrites dead xde)
  gemm_fc1<<<dim3(BL/64, 2), 256, 0, stream>>>(out, wb_fc1, m1);

  // 8. out += silu(dwconv3(m1)) @ fc2.T  (dwconv fused into A-staging)
  gemm_fc2dw<<<dim3(BL/64, 4), 256, 0, stream>>>(m1, wb_fc2, dw_w, dw_b, out);
}